// Round 13
// baseline (174.106 us; speedup 1.0000x reference)
//
#include <hip/hip_runtime.h>

// B=4, H=W=64, N=4096, C=512, HEAD=8, dh=64, SR=4, Nk=256
// Split-bf16: val = hi + lo (both bf16).
// TERMS=3: aH*bH + aL*bH + aH*bL — kv-proj only (K/V precision matters most).
// TERMS=2: aH*bH + aL*bH = full-x times rounded-W — conv, q-proj, out-proj.
// attn QK: 2-term (Khi*Qhi + Khi*Qlo); PV keeps Vhi+Vlo (V-lo error would be
// ~1e-3 direct; K-lo error is pre-softmax ~2e-4 -> negligible).

typedef __bf16 bf16x8 __attribute__((ext_vector_type(8)));
typedef float f32x4 __attribute__((ext_vector_type(4)));

__device__ __forceinline__ ushort f2bf(float v) {
  uint u = __float_as_uint(v);
  return (ushort)((u + 0x7FFFu + ((u >> 16) & 1u)) >> 16);
}
__device__ __forceinline__ float bf2f(ushort h) {
  return __uint_as_float((uint)h << 16);
}
__device__ __forceinline__ void gload16(const void* g, void* l) {
  __builtin_amdgcn_global_load_lds(
      (const __attribute__((address_space(1))) void*)g,
      (__attribute__((address_space(3))) void*)l, 16, 0, 0);
}
// bijective XCD swizzle for nwg % 8 == 0
__device__ __forceinline__ int xcd_swz(int bid, int nwg) {
  int cpx = nwg >> 3;
  return (bid & 7) * cpx + (bid >> 3);
}

// ---------------- fused prep: convert x, W's, Wsr(hi-only), biases ----------------
__global__ __launch_bounds__(256) void prep_kernel(
    const float* __restrict__ x, const float* __restrict__ Wq,
    const float* __restrict__ Wp, const float* __restrict__ Wk,
    const float* __restrict__ Wv, const float* __restrict__ Wsr,
    const float* __restrict__ bk, const float* __restrict__ bv,
    ushort* __restrict__ xq, ushort* __restrict__ Wq_,
    ushort* __restrict__ Wp_, ushort* __restrict__ Wkv_,
    ushort* __restrict__ Wsr_, float* __restrict__ bkv) {
  __shared__ float t[32][33];
  int bid = blockIdx.x, tid = threadIdx.x;
  if (bid < 4096 + 512) {
    const float* src;
    ushort* dst;
    int gid;
    bool need_lo = true;
    if (bid < 4096) {
      src = x; dst = xq; gid = bid * 256 + tid;
    } else {
      int z = (bid - 4096) >> 7;
      src = (z == 0) ? Wq : (z == 1) ? Wp : (z == 2) ? Wk : Wv;
      dst = (z == 0) ? Wq_ : (z == 1) ? Wp_ : (z == 2) ? Wkv_ : (Wkv_ + 512 * 1024);
      gid = ((bid - 4096) & 127) * 256 + tid;
      need_lo = (z >= 2);  // Wq_/Wp_ lo halves never read (TERMS=2 B-side)
    }
    int row = gid >> 6, c8 = (gid & 63) << 3;
    float4 a = *(const float4*)(src + (size_t)row * 512 + c8);
    float4 b = *(const float4*)(src + (size_t)row * 512 + c8 + 4);
    ushort h[8], l[8];
    float vv[8] = {a.x, a.y, a.z, a.w, b.x, b.y, b.z, b.w};
#pragma unroll
    for (int e = 0; e < 8; ++e) { h[e] = f2bf(vv[e]); l[e] = f2bf(vv[e] - bf2f(h[e])); }
    uint4 hp, lp;
    hp.x = h[0] | ((uint)h[1] << 16); hp.y = h[2] | ((uint)h[3] << 16);
    hp.z = h[4] | ((uint)h[5] << 16); hp.w = h[6] | ((uint)h[7] << 16);
    lp.x = l[0] | ((uint)l[1] << 16); lp.y = l[2] | ((uint)l[3] << 16);
    lp.z = l[4] | ((uint)l[5] << 16); lp.w = l[6] | ((uint)l[7] << 16);
    *(uint4*)(dst + (size_t)row * 1024 + c8) = hp;
    if (need_lo) *(uint4*)(dst + (size_t)row * 1024 + 512 + c8) = lp;
  } else if (bid < 4096 + 512 + 4096) {
    int tb = bid - 4608;
    int z = tb >> 8, rem = tb & 255;
    int ci0 = (rem >> 4) << 5, co0 = (rem & 15) << 5;
    int tx = tid & 31, ty = tid >> 5;
#pragma unroll
    for (int i = 0; i < 32; i += 8)
      t[ty + i][tx] = Wsr[((size_t)z * 512 + ci0 + ty + i) * 512 + co0 + tx];
    __syncthreads();
#pragma unroll
    for (int i = 0; i < 32; i += 8) {
      float v = t[tx][ty + i];
      int co = co0 + ty + i, ci = ci0 + tx;
      Wsr_[((size_t)z * 512 + co) * 512 + ci] = f2bf(v);  // hi only
    }
  } else {
    bkv[tid] = bk[tid]; bkv[tid + 256] = bk[tid + 256];
    bkv[tid + 512] = bv[tid]; bkv[tid + 768] = bv[tid + 256];
  }
}

// ---------------- MFMA GEMM body: double-buffered 2-phase K-loop ----------------
// TERMS=3 -> 24 K-steps (K'=1536); TERMS=2 -> 16 K-steps (K'=1024).
//   ap = kk - (kk>=1024?1024:0)  -> A: hi, lo, [hi]
//   bp = kk - (kk>=512?512:0)    -> B: hi, hi, [lo]
// EPI=0: C fp32 + bias. EPI=1: Qsplit layout (LDS-coalesced). EPI=2: Kq/Vt scatter.
template <int EPI, int TERMS>
__device__ __forceinline__ void gemm_body(
    const ushort* __restrict__ A, const ushort* __restrict__ Bw,
    const float* __restrict__ bias, float* __restrict__ C,
    ushort* __restrict__ Qs, ushort* __restrict__ Kq, ushort* __restrict__ Vt,
    int N, int bx, int by, ushort* lds) {
  constexpr int NS = TERMS * 8;  // K-steps
  int tid = threadIdx.x;
  int lane = tid & 63, w = tid >> 6;
  int wr = w >> 1, wc = w & 1;
  int l15 = lane & 15, g = lane >> 4;
  int srow = lane >> 3;
  int scol = (lane & 7) ^ srow;

  const ushort* aBase = A + (size_t)(by * 128 + w * 32 + srow) * 1024 + scol * 8;
  const ushort* bBase = Bw + (size_t)(bx * 128 + w * 32 + srow) * 1024 + scol * 8;

  f32x4 acc[4][4];
#pragma unroll
  for (int i = 0; i < 4; ++i)
#pragma unroll
    for (int j = 0; j < 4; ++j) acc[i][j] = (f32x4){0.f, 0.f, 0.f, 0.f};

#define STAGE_G(ks, buf)                                              \
  {                                                                   \
    int kk = (ks) * 64;                                               \
    int ap = kk - (kk >= 1024 ? 1024 : 0);                            \
    int bp = kk - (kk >= 512 ? 512 : 0);                              \
    ushort* aD = lds + (buf) * 16384 + w * 2048;                      \
    ushort* bD = lds + (buf) * 16384 + 8192 + w * 2048;               \
    _Pragma("unroll") for (int t = 0; t < 4; ++t) {                   \
      gload16(aBase + (size_t)t * 8192 + ap, aD + t * 512);           \
      gload16(bBase + (size_t)t * 8192 + bp, bD + t * 512);           \
    }                                                                 \
  }

#define COMPUTE_G(buf)                                                         \
  {                                                                            \
    const ushort* As = lds + (buf) * 16384;                                    \
    const ushort* Bs = As + 8192;                                              \
    _Pragma("unroll") for (int kk2 = 0; kk2 < 2; ++kk2) {                      \
      int rb = kk2 * 4 + g;                                                    \
      bf16x8 af[4], bg[4];                                                     \
      _Pragma("unroll") for (int i = 0; i < 4; ++i) {                          \
        int row = wr * 64 + i * 16 + l15;                                      \
        af[i] = *(const bf16x8*)&As[row * 64 + ((rb ^ (row & 7)) << 3)];       \
      }                                                                        \
      _Pragma("unroll") for (int j = 0; j < 4; ++j) {                          \
        int col = wc * 64 + j * 16 + l15;                                      \
        bg[j] = *(const bf16x8*)&Bs[col * 64 + ((rb ^ (col & 7)) << 3)];       \
      }                                                                        \
      _Pragma("unroll") for (int i = 0; i < 4; ++i)                            \
        _Pragma("unroll") for (int j = 0; j < 4; ++j)                          \
          acc[i][j] =                                                          \
              __builtin_amdgcn_mfma_f32_16x16x32_bf16(af[i], bg[j], acc[i][j], \
                                                      0, 0, 0);                \
    }                                                                          \
  }

  STAGE_G(0, 0);
  __syncthreads();
  for (int ks = 0; ks < NS - 1; ++ks) {
    STAGE_G(ks + 1, (ks + 1) & 1);
    COMPUTE_G(ks & 1);
    __syncthreads();
  }
  COMPUTE_G((NS - 1) & 1);

#undef STAGE_G
#undef COMPUTE_G

  if (EPI == 0) {
#pragma unroll
    for (int j = 0; j < 4; ++j) {
      int col = bx * 128 + wc * 64 + j * 16 + l15;
      float bj = bias ? bias[col] : 0.f;
#pragma unroll
      for (int i = 0; i < 4; ++i) {
        int row0 = by * 128 + wr * 64 + i * 16 + g * 4;
#pragma unroll
        for (int r = 0; r < 4; ++r)
          C[(size_t)(row0 + r) * N + col] = acc[i][j][r] + bj;
      }
    }
  } else if (EPI == 1) {
    __syncthreads();
#pragma unroll
    for (int j = 0; j < 4; ++j) {
      int cl = wc * 64 + j * 16 + l15;
      float bj = bias[bx * 128 + cl];
#pragma unroll
      for (int i = 0; i < 4; ++i) {
        int rl0 = wr * 64 + i * 16 + g * 4;
#pragma unroll
        for (int r = 0; r < 4; ++r) {
          float v = (acc[i][j][r] + bj) * 0.125f;
          ushort h = f2bf(v), lo = f2bf(v - bf2f(h));
          lds[(rl0 + r) * 128 + cl] = h;
          lds[16384 + (rl0 + r) * 128 + cl] = lo;
        }
      }
    }
    __syncthreads();
#pragma unroll
    for (int it = 0; it < 8; ++it) {
      int c = tid + it * 256;
      int r = c >> 4, ck = c & 15;
      int grow = by * 128 + r;
      size_t base = ((size_t)grow * 8 + bx * 2 + (ck >> 3)) * 128 + (ck & 7) * 8;
      *(uint4*)(Qs + base) = *(const uint4*)&lds[r * 128 + ck * 8];
      *(uint4*)(Qs + base + 64) = *(const uint4*)&lds[16384 + r * 128 + ck * 8];
    }
  } else {
    // EPI=2: kv epilogue — scatter split-bf16 directly into Kq / Vt layouts.
#pragma unroll
    for (int j = 0; j < 4; ++j) {
      int col = bx * 128 + wc * 64 + j * 16 + l15;
      float bj = bias[col];
      bool isK = col < 512;
      int cp = isK ? col : col - 512;
      int hh = cp >> 6, d = cp & 63;
#pragma unroll
      for (int i = 0; i < 4; ++i) {
        int row0 = by * 128 + wr * 64 + i * 16 + g * 4;
#pragma unroll
        for (int r = 0; r < 4; ++r) {
          int row = row0 + r;
          int b = row >> 8, kk = row & 255;
          float v = acc[i][j][r] + bj;
          ushort h = f2bf(v), lo = f2bf(v - bf2f(h));
          if (isK) {
            size_t base = ((size_t)((b * 8 + hh) * 256) + kk) * 128 + d;
            Kq[base] = h; Kq[base + 64] = lo;
          } else {
            size_t base = ((size_t)((b * 8 + hh) * 64) + d) * 512 + kk;
            Vt[base] = h; Vt[base + 256] = lo;
          }
        }
      }
    }
  }
}

// ---------------- conv body: split-8 (2 taps per block), TERMS=2 ----------------
// Wsr_ is hi-only [16 taps][512 co][512 ci]. x full (hi+lo): ap = kkt in [0,1024).
__device__ __forceinline__ void conv_body(
    const ushort* __restrict__ xq, const ushort* __restrict__ Wsr_,
    float* __restrict__ part, int bx, int by, int z, ushort* lds) {
  int tid = threadIdx.x;
  int lane = tid & 63, w = tid >> 6;
  int wr = w >> 1, wc = w & 1;
  int l15 = lane & 15, g = lane >> 4;
  int srow = lane >> 3;
  int scol = (lane & 7) ^ srow;

  const ushort* aB0[4];
  const ushort* aB1[4];
  const ushort* bB0;
  const ushort* bB1;
#pragma unroll
  for (int p = 0; p < 2; ++p) {
    int tap = z * 2 + p, kh = tap >> 2, kw = tap & 3;
#pragma unroll
    for (int t = 0; t < 4; ++t) {
      int gm = by * 128 + w * 32 + t * 8 + srow;
      int xr = (gm >> 8) * 4096 + ((((gm >> 4) & 15) << 2) + kh) * 64 +
               ((gm & 15) << 2) + kw;
      if (p == 0) aB0[t] = xq + (size_t)xr * 1024 + scol * 8;
      else        aB1[t] = xq + (size_t)xr * 1024 + scol * 8;
    }
    const ushort* bb =
        Wsr_ + ((size_t)(tap * 512 + bx * 128 + w * 32 + srow)) * 512 + scol * 8;
    if (p == 0) bB0 = bb; else bB1 = bb;
  }

  f32x4 acc[4][4];
#pragma unroll
  for (int i = 0; i < 4; ++i)
#pragma unroll
    for (int j = 0; j < 4; ++j) acc[i][j] = (f32x4){0.f, 0.f, 0.f, 0.f};

#define STAGE_C(ks, buf)                                              \
  {                                                                   \
    int tap_ = (ks) >> 4;                                             \
    int kkt = ((ks) & 15) * 64;                                       \
    int bp = kkt & 511;                                               \
    ushort* aD = lds + (buf) * 16384 + w * 2048;                      \
    ushort* bD = lds + (buf) * 16384 + 8192 + w * 2048;               \
    const ushort* bBp = tap_ ? bB1 : bB0;                             \
    _Pragma("unroll") for (int t = 0; t < 4; ++t) {                   \
      const ushort* aBp = tap_ ? aB1[t] : aB0[t];                     \
      gload16(aBp + kkt, aD + t * 512);                               \
      gload16(bBp + (size_t)t * 4096 + bp, bD + t * 512);             \
    }                                                                 \
  }

#define COMPUTE_C(buf)                                                         \
  {                                                                            \
    const ushort* As = lds + (buf) * 16384;                                    \
    const ushort* Bs = As + 8192;                                              \
    _Pragma("unroll") for (int kk2 = 0; kk2 < 2; ++kk2) {                      \
      int rb = kk2 * 4 + g;                                                    \
      bf16x8 af[4], bg[4];                                                     \
      _Pragma("unroll") for (int i = 0; i < 4; ++i) {                          \
        int row = wr * 64 + i * 16 + l15;                                      \
        af[i] = *(const bf16x8*)&As[row * 64 + ((rb ^ (row & 7)) << 3)];       \
      }                                                                        \
      _Pragma("unroll") for (int j = 0; j < 4; ++j) {                          \
        int col = wc * 64 + j * 16 + l15;                                      \
        bg[j] = *(const bf16x8*)&Bs[col * 64 + ((rb ^ (col & 7)) << 3)];       \
      }                                                                        \
      _Pragma("unroll") for (int i = 0; i < 4; ++i)                            \
        _Pragma("unroll") for (int j = 0; j < 4; ++j)                          \
          acc[i][j] =                                                          \
              __builtin_amdgcn_mfma_f32_16x16x32_bf16(af[i], bg[j], acc[i][j], \
                                                      0, 0, 0);                \
    }                                                                          \
  }

  STAGE_C(0, 0);
  __syncthreads();
  for (int ks = 0; ks < 31; ++ks) {
    STAGE_C(ks + 1, (ks + 1) & 1);
    COMPUTE_C(ks & 1);
    __syncthreads();
  }
  COMPUTE_C(1);

#undef STAGE_C
#undef COMPUTE_C

  float* Cp = part + (size_t)z * 524288;
#pragma unroll
  for (int j = 0; j < 4; ++j) {
    int col = bx * 128 + wc * 64 + j * 16 + l15;
#pragma unroll
    for (int i = 0; i < 4; ++i) {
      int row0 = by * 128 + wr * 64 + i * 16 + g * 4;
#pragma unroll
      for (int r = 0; r < 4; ++r)
        Cp[(size_t)(row0 + r) * 512 + col] = acc[i][j][r];
    }
  }
}

// conv (work-ids 0..255) + q-proj (256..767); `base` for compact two-launch path
__global__ __launch_bounds__(256) void cq_kernel(
    const ushort* __restrict__ xq, const ushort* __restrict__ Wsr_,
    float* __restrict__ part, const ushort* __restrict__ Wq_,
    const float* __restrict__ bq, ushort* __restrict__ Qs, int base) {
  __shared__ __align__(16) ushort lds[32768];
  int bid = xcd_swz(blockIdx.x, gridDim.x) + base;
  if (bid < 256) {
    conv_body(xq, Wsr_, part, bid & 3, (bid >> 2) & 7, bid >> 5, lds);
  } else {
    int b2 = bid - 256;
    gemm_body<1, 2>(xq, Wq_, bq, nullptr, Qs, nullptr, nullptr, 512,
                    b2 & 3, b2 >> 2, lds);
  }
}

// kv-proj: 64 blocks, writes Kq/Vt directly (EPI=2, TERMS=3)
__global__ __launch_bounds__(256) void kvproj_kernel(
    const ushort* __restrict__ xkv_, const ushort* __restrict__ Wkv_,
    const float* __restrict__ bkv, ushort* __restrict__ Kq,
    ushort* __restrict__ Vt) {
  __shared__ __align__(16) ushort lds[32768];
  int bid = xcd_swz(blockIdx.x, 64);
  gemm_body<2, 3>(xkv_, Wkv_, bkv, nullptr, nullptr, Kq, Vt, 1024,
                  bid & 7, bid >> 3, lds);
}

// out-proj (TERMS=2)
__global__ __launch_bounds__(256) void gemm_out_kernel(
    const ushort* __restrict__ A, const ushort* __restrict__ Bw,
    const float* __restrict__ bias, float* __restrict__ C) {
  __shared__ __align__(16) ushort lds[32768];
  int bid = xcd_swz(blockIdx.x, 512);
  gemm_body<0, 2>(A, Bw, bias, C, nullptr, nullptr, nullptr, 512,
                  bid & 3, bid >> 2, lds);
}

// ---------------- partial-sum(8) + bias + LayerNorm -> split-bf16 ----------------
__global__ __launch_bounds__(256) void ln_kernel(
    const float* __restrict__ part, const float* __restrict__ bsr,
    const float* __restrict__ gamma, const float* __restrict__ beta,
    ushort* __restrict__ xkv_) {
  int row = blockIdx.x;
  int t = threadIdx.x;
  float v0 = bsr[t], v1 = bsr[t + 256];
  for (int p = 0; p < 8; ++p) {
    v0 += part[(size_t)p * 524288 + (size_t)row * 512 + t];
    v1 += part[(size_t)p * 524288 + (size_t)row * 512 + t + 256];
  }
  float s = v0 + v1, sq = v0 * v0 + v1 * v1;
#pragma unroll
  for (int o = 1; o < 64; o <<= 1) {
    s += __shfl_xor(s, o);
    sq += __shfl_xor(sq, o);
  }
  __shared__ float red[8];
  int wv = t >> 6;
  if ((t & 63) == 0) { red[wv] = s; red[4 + wv] = sq; }
  __syncthreads();
  s = red[0] + red[1] + red[2] + red[3];
  sq = red[4] + red[5] + red[6] + red[7];
  float mu = s * (1.0f / 512.0f);
  float var = sq * (1.0f / 512.0f) - mu * mu;
  float rs = rsqrtf(var + 1e-5f);
  float y0 = (v0 - mu) * rs * gamma[t] + beta[t];
  float y1 = (v1 - mu) * rs * gamma[t + 256] + beta[t + 256];
  ushort h0 = f2bf(y0), h1 = f2bf(y1);
  xkv_[(size_t)row * 1024 + t] = h0;
  xkv_[(size_t)row * 1024 + t + 256] = h1;
  xkv_[(size_t)row * 1024 + 512 + t] = f2bf(y0 - bf2f(h0));
  xkv_[(size_t)row * 1024 + 512 + t + 256] = f2bf(y1 - bf2f(h1));
}

// ---------------- MFMA flash attention: 128 q/block, QK 2-term, dbuf DMA ----------------
__global__ __launch_bounds__(256, 2) void attn_kernel(
    const ushort* __restrict__ Qs, const ushort* __restrict__ Kq,
    const ushort* __restrict__ Vt, ushort* __restrict__ attno) {
  __shared__ __align__(16) char arena[65536];
  ushort* KsL = (ushort*)arena;            // [2][64 kk][64 hi], swizzled (8KB/buf)
  ushort* VtL = (ushort*)(arena + 16384);  // [2][64 d][128 hi|lo kk] (16KB/buf)
  ushort* PL = (ushort*)(arena + 49152);   // [128 q][64 kk] bf16, swizzled
  float* ob = (float*)arena;               // epilogue alias

  int tid = threadIdx.x;
  int qb = blockIdx.x, h = blockIdx.y, b = blockIdx.z;
  int n0 = qb * 128, bh = b * 8 + h;
  int lane = tid & 63, w = tid >> 6;
  int q15 = lane & 15, g = lane >> 4;

  const ushort* kbase = Kq + (size_t)bh * 256 * 128;
  const ushort* vbase = Vt + (size_t)bh * 64 * 512;

  bf16x8 qf[2][2][2];
#pragma unroll
  for (int set = 0; set < 2; ++set) {
    const ushort* qptr =
        Qs + ((size_t)(b * 4096 + n0 + set * 64 + w * 16 + q15) * 8 + h) * 128;
#pragma unroll
    for (int s = 0; s < 2; ++s)
#pragma unroll
      for (int kb = 0; kb < 2; ++kb)
        qf[set][s][kb] = *(const bf16x8*)(qptr + s * 64 + kb * 32 + g * 8);
  }

  f32x4 accO[2][4];
#pragma unroll
  for (int set = 0; set < 2; ++set)
#pragma unroll
    for (int t = 0; t < 4; ++t) accO[set][t] = (f32x4){0.f, 0.f, 0.f, 0.f};
  float m[2] = {-1e30f, -1e30f}, l[2] = {0.f, 0.f};

  // K: hi-only, 8 rows/instr (64 lanes x 16B = 1KB = 8 rows of 128B).
  // V: hi|lo, 4 rows/instr. Pre-swizzled global source, linear LDS dest.
#define STAGE_A(cc, buf)                                                     \
  {                                                                          \
    _Pragma("unroll") for (int i = 0; i < 2; ++i) {                          \
      int rb_ = w * 16 + i * 8;                                              \
      int r_ = rb_ + (lane >> 3);                                            \
      int sb_ = (lane & 7) ^ (r_ & 7);                                       \
      gload16(kbase + (size_t)((cc) * 64 + r_) * 128 + (sb_ << 3),           \
              KsL + (buf) * 4096 + rb_ * 64);                                \
    }                                                                        \
    _Pragma("unroll") for (int i = 0; i < 4; ++i) {                          \
      int rb_ = w * 16 + i * 4;                                              \
      int r_ = rb_ + (lane >> 4);                                            \
      int sb_ = (lane & 15) ^ (r_ & 7);                                      \
      gload16(vbase + (size_t)r_ * 512 + ((sb_ >> 3) << 8) + (cc) * 64 +     \
                  ((sb_ & 7) << 3),                                          \
              VtL + (buf) * 8192 + rb_ * 128);                               \
    }                                                                        \
  }

  STAGE_A(0, 0);
  __syncthreads();

  for (int c = 0; c < 4; ++c) {
    int buf = c & 1;
    if (c < 3) STAGE_A(c + 1, buf ^ 1);
    const ushort* Ks = KsL + buf * 4096;
    const ushort* Vs = VtL + buf * 8192;

    // S^T = Khi*Qhi + Khi*Qlo (2-term)
    f32x4 accS[2][4];
#pragma unroll
    for (int set = 0; set < 2; ++set)
#pragma unroll
      for (int t = 0; t < 4; ++t) accS[set][t] = (f32x4){0.f, 0.f, 0.f, 0.f};
#pragma unroll
    for (int kb = 0; kb < 2; ++kb) {
      bf16x8 ak[4];
#pragma unroll
      for (int t = 0; t < 4; ++t) {
        int kkr = t * 16 + q15;
        ak[t] = *(const bf16x8*)&Ks[kkr * 64 + (((kb * 4 + g) ^ (kkr & 7)) << 3)];
      }
#pragma unroll
      for (int set = 0; set < 2; ++set) {
#pragma unroll
        for (int t = 0; t < 4; ++t)
          accS[set][t] = __builtin_amdgcn_mfma_f32_16x16x32_bf16(
              ak[t], qf[set][0][kb], accS[set][t], 0, 0, 0);
#pragma unroll
        for (int t = 0; t < 4; ++t)
          accS[set][t] = __builtin_amdgcn_mfma_f32_16x16x32_bf16(
              ak[t], qf[set][1][kb], accS[set][t], 0, 0, 0);
      }
    }

#pragma unroll
    for (int set = 0; set < 2; ++set) {
      int qrowL = set * 64 + w * 16 + q15;
      float mx = -1e30f;
#pragma unroll
      for (int t = 0; t < 4; ++t)
#pragma unroll
        for (int r = 0; r < 4; ++r) mx = fmaxf(mx, accS[set][t][r]);
      mx = fmaxf(mx, __shfl_xor(mx, 16));
      mx = fmaxf(mx, __shfl_xor(mx, 32));
      float mn = fmaxf(m[set], mx);
      float fac = __expf(m[set] - mn);
      m[set] = mn;
      float sum = 0.f;
      ushort ph[4][4];
#pragma unroll
      for (int t = 0; t < 4; ++t)
#pragma unroll
        for (int r = 0; r < 4; ++r) {
          float p = __expf(accS[set][t][r] - mn);
          ushort hp = f2bf(p);
          ph[t][r] = hp;
          sum += bf2f(hp);
        }
      sum += __shfl_xor(sum, 16);
      sum += __shfl_xor(sum, 32);
      l[set] = l[set] * fac + sum;
#pragma unroll
      for (int t = 0; t < 4; ++t) {
        accO[set][t][0] *= fac; accO[set][t][1] *= fac;
        accO[set][t][2] *= fac; accO[set][t][3] *= fac;
      }
#pragma unroll
      for (int t = 0; t < 4; ++t)
#pragma unroll
        for (int rp = 0; rp < 4; rp += 2) {
          uint u = ph[t][rp] | ((uint)ph[t][rp + 1] << 16);
          int kkl = t * 16 + g * 4 + rp;
          int blk = kkl >> 3, off = kkl & 7;
          *(uint*)((char*)PL + qrowL * 128 + ((blk ^ (q15 & 7)) << 4) + off * 2) = u;
        }
    }
    __syncthreads();

    bf16x8 pf[2][2];
#pragma unroll
    for (int set = 0; set < 2; ++set) {
      int qrowL = set * 64 + w * 16 + q15;
#pragma unroll
      for (int kb = 0; kb < 2; ++kb)
        pf[set][kb] = *(const bf16x8*)((char*)PL + qrowL * 128 +
                                       (((kb * 4 + g) ^ (q15 & 7)) << 4));
    }
#pragma unroll
    for (int s = 0; s < 2; ++s)
#pragma unroll
      for (int kb = 0; kb < 2; ++kb)
#pragma unroll
        for (int t = 0; t < 4; ++t) {
          int d = t * 16 + q15;
          bf16x8 vf =
              *(const bf16x8*)&Vs[d * 128 + (((s * 8 + kb * 4 + g) ^ (d & 7)) << 3)];
          accO[0][t] = __builtin_amdgcn_mfma_f32_16x16x32_bf16(vf, pf[0][kb],
                                                               accO[0][t], 0, 0, 0);
          accO[1][t] = __builtin_amdgcn_mfma_f32_16x16x32_bf16(vf, pf[1][kb],
                                                               accO[1][t], 0, 0, 0);
        }
    __syncthreads();
  }
#undef STAGE_A

#pragma unroll
  for (int set = 0; set < 2; ++set) {
    if (set) __syncthreads();
    float inv = 1.0f / l[set];
#pragma unroll
    for (int t = 0; t < 4; ++t)
#pragma unroll
      for (int r = 0; r < 4; ++r)
        ob[(t * 16 + g * 4 + r) * 68 + w * 16 + q15] = accO[set][t][r] * inv;
    __syncthreads();
#pragma unroll
    for (int i = 0; i < 2; ++i) {
      int idx = tid + i * 256;
      int qq = idx >> 3, d8 = (idx & 7) << 3;
      ushort hh[8], ll[8];
#pragma unroll
      for (int jj = 0; jj < 8; ++jj) {
        float v = ob[(d8 + jj) * 68 + qq];
        hh[jj] = f2bf(v);
        ll[jj] = f2bf(v - bf2f(hh[jj]));
      }
      uint4 hp, lp;
      hp.x = hh[0] | ((uint)hh[1] << 16); hp.y = hh[2] | ((uint)hh[3] << 16);
      hp.z = hh[4] | ((uint)hh[5] << 16); hp.w = hh[6] | ((uint)hh[7] << 16);
      lp.x = ll[0] | ((uint)ll[1] << 16); lp.y = ll[2] | ((uint)ll[3] << 16);
      lp.z = ll[4] | ((uint)ll[5] << 16); lp.w = ll[6] | ((uint)ll[7] << 16);
      size_t rowb = (size_t)(b * 4096 + n0 + set * 64 + qq) * 1024 + h * 64 + d8;
      *(uint4*)(attno + rowb) = hp;
      *(uint4*)(attno + rowb + 512) = lp;
    }
  }
}

// ---------------- launch ----------------
extern "C" void kernel_launch(void* const* d_in, const int* in_sizes, int n_in,
                              void* d_out, int out_size, void* d_ws, size_t ws_size,
                              hipStream_t stream) {
  const float* x     = (const float*)d_in[0];
  const float* Wq    = (const float*)d_in[1];
  const float* bq    = (const float*)d_in[2];
  const float* Wk    = (const float*)d_in[3];
  const float* bk    = (const float*)d_in[4];
  const float* Wv    = (const float*)d_in[5];
  const float* bv    = (const float*)d_in[6];
  const float* Wp    = (const float*)d_in[7];
  const float* bp    = (const float*)d_in[8];
  const float* Wsr   = (const float*)d_in[9];
  const float* bsr   = (const float*)d_in[10];
  const float* gamma = (const float*)d_in[11];
  const float* beta  = (const float*)d_in[12];

  float* ws = (float*)d_ws;
  // bigws layout: xq/attno 8.39M | conv_part 4.19M | Qsplit 8.39M | Wsr_ 2.10M |
  //               rest 2.62M  => end = 25,691,136 fl = 102,764,544 bytes.
  bool bigws = ws_size >= 102764544ull;

  ushort* xq     = (ushort*)ws;
  ushort* attno_ = (ushort*)ws;
  float*  conv_part = ws + 8388608;             // [8][1024][512] f32 = 4,194,304 fl
  ushort* Qsplit = bigws ? (ushort*)(ws + 12582912)
                         : (ushort*)(ws + 8388608);   // compact: aliases conv_part
  size_t tail = bigws ? 20971520 : 16777216;
  ushort* Wsr_ = (ushort*)(ws + tail);          // hi-only: 4,194,304 us = 2,097,152 fl
  float*  rest = ws + tail + 2097152;
  ushort* Wq_  = (ushort*)rest;                 // 524,288 us = 262,144 fl
  ushort* Wp_  = (ushort*)(rest + 262144);      // 524,288 us = 262,144 fl
  ushort* Wkv_ = (ushort*)(rest + 524288);      // 1,048,576 us = 524,288 fl
  ushort* xkv_ = (ushort*)(rest + 1048576);     // 1,048,576 us = 524,288 fl
  ushort* Kq   = (ushort*)(rest + 1572864);     // 1,048,576 us = 524,288 fl
  ushort* Vt   = (ushort*)(rest + 2097152);     // 1,048,576 us = 524,288 fl
  float*  bkv  = rest + 2621440;                // 1,024 fl
  float* outp = (float*)d_out;

  prep_kernel<<<8705, 256, 0, stream>>>(x, Wq, Wp, Wk, Wv, Wsr, bk, bv,
                                        xq, Wq_, Wp_, Wkv_, Wsr_, bkv);
  if (bigws) {
    // conv (256 ids) + q-proj (512 ids) concurrent
    cq_kernel<<<768, 256, 0, stream>>>(xq, Wsr_, conv_part, Wq_, bq, Qsplit, 0);
    ln_kernel<<<1024, 256, 0, stream>>>(conv_part, bsr, gamma, beta, xkv_);
  } else {
    cq_kernel<<<256, 256, 0, stream>>>(xq, Wsr_, conv_part, Wq_, bq, Qsplit, 0);
    ln_kernel<<<1024, 256, 0, stream>>>(conv_part, bsr, gamma, beta, xkv_);
    cq_kernel<<<512, 256, 0, stream>>>(xq, Wsr_, conv_part, Wq_, bq, Qsplit, 256);
  }
  kvproj_kernel<<<64, 256, 0, stream>>>(xkv_, Wkv_, bkv, Kq, Vt);
  attn_kernel<<<dim3(32, 8, 4), 256, 0, stream>>>(Qsplit, Kq, Vt, attno_);
  gemm_out_kernel<<<512, 256, 0, stream>>>(attno_, Wp_, bp, outp);
}

// Round 14
// 157.655 us; speedup vs baseline: 1.1043x; 1.1043x over previous
//
#include <hip/hip_runtime.h>

// B=4, H=W=64, N=4096, C=512, HEAD=8, dh=64, SR=4, Nk=256
// Split-bf16: val = hi + lo (both bf16).
// TERMS=3: aH*bH + aL*bH + aH*bL — kv-proj only.
// TERMS=2: aH*bH + aL*bH — conv, q-proj, out-proj.
// attn QK: 2-term (Khi*Qhi + Khi*Qlo); PV keeps Vhi+Vlo.
// LESSON r13: keep GEMM-family launches UNIFORM in K-steps — xcd_swz
// concentrates low work-ids on few XCDs, so mixed-length blocks straggle.

typedef __bf16 bf16x8 __attribute__((ext_vector_type(8)));
typedef float f32x4 __attribute__((ext_vector_type(4)));

__device__ __forceinline__ ushort f2bf(float v) {
  uint u = __float_as_uint(v);
  return (ushort)((u + 0x7FFFu + ((u >> 16) & 1u)) >> 16);
}
__device__ __forceinline__ float bf2f(ushort h) {
  return __uint_as_float((uint)h << 16);
}
__device__ __forceinline__ void gload16(const void* g, void* l) {
  __builtin_amdgcn_global_load_lds(
      (const __attribute__((address_space(1))) void*)g,
      (__attribute__((address_space(3))) void*)l, 16, 0, 0);
}
// bijective XCD swizzle for nwg % 8 == 0
__device__ __forceinline__ int xcd_swz(int bid, int nwg) {
  int cpx = nwg >> 3;
  return (bid & 7) * cpx + (bid >> 3);
}

// ---------------- fused prep: convert x, W's, Wsr(hi-only), biases ----------------
__global__ __launch_bounds__(256) void prep_kernel(
    const float* __restrict__ x, const float* __restrict__ Wq,
    const float* __restrict__ Wp, const float* __restrict__ Wk,
    const float* __restrict__ Wv, const float* __restrict__ Wsr,
    const float* __restrict__ bk, const float* __restrict__ bv,
    ushort* __restrict__ xq, ushort* __restrict__ Wq_,
    ushort* __restrict__ Wp_, ushort* __restrict__ Wkv_,
    ushort* __restrict__ Wsr_, float* __restrict__ bkv) {
  __shared__ float t[32][33];
  int bid = blockIdx.x, tid = threadIdx.x;
  if (bid < 4096 + 512) {
    const float* src;
    ushort* dst;
    int gid;
    bool need_lo = true;
    if (bid < 4096) {
      src = x; dst = xq; gid = bid * 256 + tid;
    } else {
      int z = (bid - 4096) >> 7;
      src = (z == 0) ? Wq : (z == 1) ? Wp : (z == 2) ? Wk : Wv;
      dst = (z == 0) ? Wq_ : (z == 1) ? Wp_ : (z == 2) ? Wkv_ : (Wkv_ + 512 * 1024);
      gid = ((bid - 4096) & 127) * 256 + tid;
      need_lo = (z >= 2);  // Wq_/Wp_ lo halves never read (TERMS=2 B-side)
    }
    int row = gid >> 6, c8 = (gid & 63) << 3;
    float4 a = *(const float4*)(src + (size_t)row * 512 + c8);
    float4 b = *(const float4*)(src + (size_t)row * 512 + c8 + 4);
    ushort h[8], l[8];
    float vv[8] = {a.x, a.y, a.z, a.w, b.x, b.y, b.z, b.w};
#pragma unroll
    for (int e = 0; e < 8; ++e) { h[e] = f2bf(vv[e]); l[e] = f2bf(vv[e] - bf2f(h[e])); }
    uint4 hp, lp;
    hp.x = h[0] | ((uint)h[1] << 16); hp.y = h[2] | ((uint)h[3] << 16);
    hp.z = h[4] | ((uint)h[5] << 16); hp.w = h[6] | ((uint)h[7] << 16);
    lp.x = l[0] | ((uint)l[1] << 16); lp.y = l[2] | ((uint)l[3] << 16);
    lp.z = l[4] | ((uint)l[5] << 16); lp.w = l[6] | ((uint)l[7] << 16);
    *(uint4*)(dst + (size_t)row * 1024 + c8) = hp;
    if (need_lo) *(uint4*)(dst + (size_t)row * 1024 + 512 + c8) = lp;
  } else if (bid < 4096 + 512 + 4096) {
    int tb = bid - 4608;
    int z = tb >> 8, rem = tb & 255;
    int ci0 = (rem >> 4) << 5, co0 = (rem & 15) << 5;
    int tx = tid & 31, ty = tid >> 5;
#pragma unroll
    for (int i = 0; i < 32; i += 8)
      t[ty + i][tx] = Wsr[((size_t)z * 512 + ci0 + ty + i) * 512 + co0 + tx];
    __syncthreads();
#pragma unroll
    for (int i = 0; i < 32; i += 8) {
      float v = t[tx][ty + i];
      int co = co0 + ty + i, ci = ci0 + tx;
      Wsr_[((size_t)z * 512 + co) * 512 + ci] = f2bf(v);  // hi only, stride 512
    }
  } else {
    bkv[tid] = bk[tid]; bkv[tid + 256] = bk[tid + 256];
    bkv[tid + 512] = bv[tid]; bkv[tid + 768] = bv[tid + 256];
  }
}

// ---------------- MFMA GEMM body: double-buffered 2-phase K-loop ----------------
// TERMS=3 -> 24 K-steps (K'=1536); TERMS=2 -> 16 K-steps (K'=1024).
//   ap = kk - (kk>=1024?1024:0)  -> A: hi, lo, [hi]
//   bp = kk - (kk>=512?512:0)    -> B: hi, hi, [lo]
// EPI=0: C fp32 + bias. EPI=1: Qsplit layout (LDS-coalesced). EPI=2: Kq/Vt scatter.
template <int EPI, int TERMS>
__device__ __forceinline__ void gemm_body(
    const ushort* __restrict__ A, const ushort* __restrict__ Bw,
    const float* __restrict__ bias, float* __restrict__ C,
    ushort* __restrict__ Qs, ushort* __restrict__ Kq, ushort* __restrict__ Vt,
    int N, int bx, int by, ushort* lds) {
  constexpr int NS = TERMS * 8;  // K-steps
  int tid = threadIdx.x;
  int lane = tid & 63, w = tid >> 6;
  int wr = w >> 1, wc = w & 1;
  int l15 = lane & 15, g = lane >> 4;
  int srow = lane >> 3;
  int scol = (lane & 7) ^ srow;

  const ushort* aBase = A + (size_t)(by * 128 + w * 32 + srow) * 1024 + scol * 8;
  const ushort* bBase = Bw + (size_t)(bx * 128 + w * 32 + srow) * 1024 + scol * 8;

  f32x4 acc[4][4];
#pragma unroll
  for (int i = 0; i < 4; ++i)
#pragma unroll
    for (int j = 0; j < 4; ++j) acc[i][j] = (f32x4){0.f, 0.f, 0.f, 0.f};

#define STAGE_G(ks, buf)                                              \
  {                                                                   \
    int kk = (ks) * 64;                                               \
    int ap = kk - (kk >= 1024 ? 1024 : 0);                            \
    int bp = kk - (kk >= 512 ? 512 : 0);                              \
    ushort* aD = lds + (buf) * 16384 + w * 2048;                      \
    ushort* bD = lds + (buf) * 16384 + 8192 + w * 2048;               \
    _Pragma("unroll") for (int t = 0; t < 4; ++t) {                   \
      gload16(aBase + (size_t)t * 8192 + ap, aD + t * 512);           \
      gload16(bBase + (size_t)t * 8192 + bp, bD + t * 512);           \
    }                                                                 \
  }

#define COMPUTE_G(buf)                                                         \
  {                                                                            \
    const ushort* As = lds + (buf) * 16384;                                    \
    const ushort* Bs = As + 8192;                                              \
    _Pragma("unroll") for (int kk2 = 0; kk2 < 2; ++kk2) {                      \
      int rb = kk2 * 4 + g;                                                    \
      bf16x8 af[4], bg[4];                                                     \
      _Pragma("unroll") for (int i = 0; i < 4; ++i) {                          \
        int row = wr * 64 + i * 16 + l15;                                      \
        af[i] = *(const bf16x8*)&As[row * 64 + ((rb ^ (row & 7)) << 3)];       \
      }                                                                        \
      _Pragma("unroll") for (int j = 0; j < 4; ++j) {                          \
        int col = wc * 64 + j * 16 + l15;                                      \
        bg[j] = *(const bf16x8*)&Bs[col * 64 + ((rb ^ (col & 7)) << 3)];       \
      }                                                                        \
      _Pragma("unroll") for (int i = 0; i < 4; ++i)                            \
        _Pragma("unroll") for (int j = 0; j < 4; ++j)                          \
          acc[i][j] =                                                          \
              __builtin_amdgcn_mfma_f32_16x16x32_bf16(af[i], bg[j], acc[i][j], \
                                                      0, 0, 0);                \
    }                                                                          \
  }

  STAGE_G(0, 0);
  __syncthreads();
  for (int ks = 0; ks < NS - 1; ++ks) {
    STAGE_G(ks + 1, (ks + 1) & 1);
    COMPUTE_G(ks & 1);
    __syncthreads();
  }
  COMPUTE_G((NS - 1) & 1);

#undef STAGE_G
#undef COMPUTE_G

  if (EPI == 0) {
#pragma unroll
    for (int j = 0; j < 4; ++j) {
      int col = bx * 128 + wc * 64 + j * 16 + l15;
      float bj = bias ? bias[col] : 0.f;
#pragma unroll
      for (int i = 0; i < 4; ++i) {
        int row0 = by * 128 + wr * 64 + i * 16 + g * 4;
#pragma unroll
        for (int r = 0; r < 4; ++r)
          C[(size_t)(row0 + r) * N + col] = acc[i][j][r] + bj;
      }
    }
  } else if (EPI == 1) {
    __syncthreads();
#pragma unroll
    for (int j = 0; j < 4; ++j) {
      int cl = wc * 64 + j * 16 + l15;
      float bj = bias[bx * 128 + cl];
#pragma unroll
      for (int i = 0; i < 4; ++i) {
        int rl0 = wr * 64 + i * 16 + g * 4;
#pragma unroll
        for (int r = 0; r < 4; ++r) {
          float v = (acc[i][j][r] + bj) * 0.125f;
          ushort h = f2bf(v), lo = f2bf(v - bf2f(h));
          lds[(rl0 + r) * 128 + cl] = h;
          lds[16384 + (rl0 + r) * 128 + cl] = lo;
        }
      }
    }
    __syncthreads();
#pragma unroll
    for (int it = 0; it < 8; ++it) {
      int c = tid + it * 256;
      int r = c >> 4, ck = c & 15;
      int grow = by * 128 + r;
      size_t base = ((size_t)grow * 8 + bx * 2 + (ck >> 3)) * 128 + (ck & 7) * 8;
      *(uint4*)(Qs + base) = *(const uint4*)&lds[r * 128 + ck * 8];
      *(uint4*)(Qs + base + 64) = *(const uint4*)&lds[16384 + r * 128 + ck * 8];
    }
  } else {
    // EPI=2: kv epilogue — scatter split-bf16 directly into Kq / Vt layouts.
#pragma unroll
    for (int j = 0; j < 4; ++j) {
      int col = bx * 128 + wc * 64 + j * 16 + l15;
      float bj = bias[col];
      bool isK = col < 512;
      int cp = isK ? col : col - 512;
      int hh = cp >> 6, d = cp & 63;
#pragma unroll
      for (int i = 0; i < 4; ++i) {
        int row0 = by * 128 + wr * 64 + i * 16 + g * 4;
#pragma unroll
        for (int r = 0; r < 4; ++r) {
          int row = row0 + r;
          int b = row >> 8, kk = row & 255;
          float v = acc[i][j][r] + bj;
          ushort h = f2bf(v), lo = f2bf(v - bf2f(h));
          if (isK) {
            size_t base = ((size_t)((b * 8 + hh) * 256) + kk) * 128 + d;
            Kq[base] = h; Kq[base + 64] = lo;
          } else {
            size_t base = ((size_t)((b * 8 + hh) * 64) + d) * 512 + kk;
            Vt[base] = h; Vt[base + 256] = lo;
          }
        }
      }
    }
  }
}

// ---------------- conv body: split-16 (ONE tap per block), TERMS=2, 16 steps ----------
// Wsr_ hi-only [16 taps][512 co][512 ci]. x full split: ap = kk in [0,1024).
__device__ __forceinline__ void conv_body(
    const ushort* __restrict__ xq, const ushort* __restrict__ Wsr_,
    float* __restrict__ part, int bx, int by, int z, ushort* lds) {
  int kh = z >> 2, kw = z & 3;
  int tid = threadIdx.x;
  int lane = tid & 63, w = tid >> 6;
  int wr = w >> 1, wc = w & 1;
  int l15 = lane & 15, g = lane >> 4;
  int srow = lane >> 3;
  int scol = (lane & 7) ^ srow;

  const ushort* aBase[4];
#pragma unroll
  for (int t = 0; t < 4; ++t) {
    int gm = by * 128 + w * 32 + t * 8 + srow;
    int xr = (gm >> 8) * 4096 + ((((gm >> 4) & 15) << 2) + kh) * 64 +
             ((gm & 15) << 2) + kw;
    aBase[t] = xq + (size_t)xr * 1024 + scol * 8;
  }
  const ushort* bBase =
      Wsr_ + ((size_t)(z * 512 + bx * 128 + w * 32 + srow)) * 512 + scol * 8;

  f32x4 acc[4][4];
#pragma unroll
  for (int i = 0; i < 4; ++i)
#pragma unroll
    for (int j = 0; j < 4; ++j) acc[i][j] = (f32x4){0.f, 0.f, 0.f, 0.f};

#define STAGE_C(ks, buf)                                              \
  {                                                                   \
    int kk = (ks) * 64;                                               \
    int bp = kk - (kk >= 512 ? 512 : 0);                              \
    ushort* aD = lds + (buf) * 16384 + w * 2048;                      \
    ushort* bD = lds + (buf) * 16384 + 8192 + w * 2048;               \
    _Pragma("unroll") for (int t = 0; t < 4; ++t) {                   \
      gload16(aBase[t] + kk, aD + t * 512);                           \
      gload16(bBase + (size_t)t * 4096 + bp, bD + t * 512);           \
    }                                                                 \
  }

#define COMPUTE_C(buf)                                                         \
  {                                                                            \
    const ushort* As = lds + (buf) * 16384;                                    \
    const ushort* Bs = As + 8192;                                              \
    _Pragma("unroll") for (int kk2 = 0; kk2 < 2; ++kk2) {                      \
      int rb = kk2 * 4 + g;                                                    \
      bf16x8 af[4], bg[4];                                                     \
      _Pragma("unroll") for (int i = 0; i < 4; ++i) {                          \
        int row = wr * 64 + i * 16 + l15;                                      \
        af[i] = *(const bf16x8*)&As[row * 64 + ((rb ^ (row & 7)) << 3)];       \
      }                                                                        \
      _Pragma("unroll") for (int j = 0; j < 4; ++j) {                          \
        int col = wc * 64 + j * 16 + l15;                                      \
        bg[j] = *(const bf16x8*)&Bs[col * 64 + ((rb ^ (col & 7)) << 3)];       \
      }                                                                        \
      _Pragma("unroll") for (int i = 0; i < 4; ++i)                            \
        _Pragma("unroll") for (int j = 0; j < 4; ++j)                          \
          acc[i][j] =                                                          \
              __builtin_amdgcn_mfma_f32_16x16x32_bf16(af[i], bg[j], acc[i][j], \
                                                      0, 0, 0);                \
    }                                                                          \
  }

  STAGE_C(0, 0);
  __syncthreads();
  for (int ks = 0; ks < 15; ++ks) {
    STAGE_C(ks + 1, (ks + 1) & 1);
    COMPUTE_C(ks & 1);
    __syncthreads();
  }
  COMPUTE_C(1);

#undef STAGE_C
#undef COMPUTE_C

  float* Cp = part + (size_t)z * 524288;
#pragma unroll
  for (int j = 0; j < 4; ++j) {
    int col = bx * 128 + wc * 64 + j * 16 + l15;
#pragma unroll
    for (int i = 0; i < 4; ++i) {
      int row0 = by * 128 + wr * 64 + i * 16 + g * 4;
#pragma unroll
      for (int r = 0; r < 4; ++r)
        Cp[(size_t)(row0 + r) * 512 + col] = acc[i][j][r];
    }
  }
}

// conv (work-ids 0..511, 16 steps) + q-proj (512..1023, 16 steps) — uniform
__global__ __launch_bounds__(256) void cq_kernel(
    const ushort* __restrict__ xq, const ushort* __restrict__ Wsr_,
    float* __restrict__ part, const ushort* __restrict__ Wq_,
    const float* __restrict__ bq, ushort* __restrict__ Qs, int base) {
  __shared__ __align__(16) ushort lds[32768];
  int bid = xcd_swz(blockIdx.x, gridDim.x) + base;
  if (bid < 512) {
    conv_body(xq, Wsr_, part, bid & 3, (bid >> 2) & 7, bid >> 5, lds);
  } else {
    int b2 = bid - 512;
    gemm_body<1, 2>(xq, Wq_, bq, nullptr, Qs, nullptr, nullptr, 512,
                    b2 & 3, b2 >> 2, lds);
  }
}

// kv-proj: 64 blocks, writes Kq/Vt directly (EPI=2, TERMS=3)
__global__ __launch_bounds__(256) void kvproj_kernel(
    const ushort* __restrict__ xkv_, const ushort* __restrict__ Wkv_,
    const float* __restrict__ bkv, ushort* __restrict__ Kq,
    ushort* __restrict__ Vt) {
  __shared__ __align__(16) ushort lds[32768];
  int bid = xcd_swz(blockIdx.x, 64);
  gemm_body<2, 3>(xkv_, Wkv_, bkv, nullptr, nullptr, Kq, Vt, 1024,
                  bid & 7, bid >> 3, lds);
}

// out-proj (TERMS=2)
__global__ __launch_bounds__(256) void gemm_out_kernel(
    const ushort* __restrict__ A, const ushort* __restrict__ Bw,
    const float* __restrict__ bias, float* __restrict__ C) {
  __shared__ __align__(16) ushort lds[32768];
  int bid = xcd_swz(blockIdx.x, 512);
  gemm_body<0, 2>(A, Bw, bias, C, nullptr, nullptr, nullptr, 512,
                  bid & 3, bid >> 2, lds);
}

// ---------------- partial-sum(16) + bias + LayerNorm -> split-bf16 ----------------
__global__ __launch_bounds__(256) void ln_kernel(
    const float* __restrict__ part, const float* __restrict__ bsr,
    const float* __restrict__ gamma, const float* __restrict__ beta,
    ushort* __restrict__ xkv_) {
  int row = blockIdx.x;
  int t = threadIdx.x;
  float v0 = bsr[t], v1 = bsr[t + 256];
  for (int p = 0; p < 16; ++p) {
    v0 += part[(size_t)p * 524288 + (size_t)row * 512 + t];
    v1 += part[(size_t)p * 524288 + (size_t)row * 512 + t + 256];
  }
  float s = v0 + v1, sq = v0 * v0 + v1 * v1;
#pragma unroll
  for (int o = 1; o < 64; o <<= 1) {
    s += __shfl_xor(s, o);
    sq += __shfl_xor(sq, o);
  }
  __shared__ float red[8];
  int wv = t >> 6;
  if ((t & 63) == 0) { red[wv] = s; red[4 + wv] = sq; }
  __syncthreads();
  s = red[0] + red[1] + red[2] + red[3];
  sq = red[4] + red[5] + red[6] + red[7];
  float mu = s * (1.0f / 512.0f);
  float var = sq * (1.0f / 512.0f) - mu * mu;
  float rs = rsqrtf(var + 1e-5f);
  float y0 = (v0 - mu) * rs * gamma[t] + beta[t];
  float y1 = (v1 - mu) * rs * gamma[t + 256] + beta[t + 256];
  ushort h0 = f2bf(y0), h1 = f2bf(y1);
  xkv_[(size_t)row * 1024 + t] = h0;
  xkv_[(size_t)row * 1024 + t + 256] = h1;
  xkv_[(size_t)row * 1024 + 512 + t] = f2bf(y0 - bf2f(h0));
  xkv_[(size_t)row * 1024 + 512 + t + 256] = f2bf(y1 - bf2f(h1));
}

// ---------------- MFMA flash attention: 128 q/block, QK 2-term, dbuf DMA ----------------
__global__ __launch_bounds__(256, 2) void attn_kernel(
    const ushort* __restrict__ Qs, const ushort* __restrict__ Kq,
    const ushort* __restrict__ Vt, ushort* __restrict__ attno) {
  __shared__ __align__(16) char arena[65536];
  ushort* KsL = (ushort*)arena;            // [2][64 kk][64 hi], swizzled (8KB/buf)
  ushort* VtL = (ushort*)(arena + 16384);  // [2][64 d][128 hi|lo kk] (16KB/buf)
  ushort* PL = (ushort*)(arena + 49152);   // [128 q][64 kk] bf16, swizzled
  float* ob = (float*)arena;               // epilogue alias

  int tid = threadIdx.x;
  int qb = blockIdx.x, h = blockIdx.y, b = blockIdx.z;
  int n0 = qb * 128, bh = b * 8 + h;
  int lane = tid & 63, w = tid >> 6;
  int q15 = lane & 15, g = lane >> 4;

  const ushort* kbase = Kq + (size_t)bh * 256 * 128;
  const ushort* vbase = Vt + (size_t)bh * 64 * 512;

  bf16x8 qf[2][2][2];
#pragma unroll
  for (int set = 0; set < 2; ++set) {
    const ushort* qptr =
        Qs + ((size_t)(b * 4096 + n0 + set * 64 + w * 16 + q15) * 8 + h) * 128;
#pragma unroll
    for (int s = 0; s < 2; ++s)
#pragma unroll
      for (int kb = 0; kb < 2; ++kb)
        qf[set][s][kb] = *(const bf16x8*)(qptr + s * 64 + kb * 32 + g * 8);
  }

  f32x4 accO[2][4];
#pragma unroll
  for (int set = 0; set < 2; ++set)
#pragma unroll
    for (int t = 0; t < 4; ++t) accO[set][t] = (f32x4){0.f, 0.f, 0.f, 0.f};
  float m[2] = {-1e30f, -1e30f}, l[2] = {0.f, 0.f};

#define STAGE_A(cc, buf)                                                     \
  {                                                                          \
    _Pragma("unroll") for (int i = 0; i < 2; ++i) {                          \
      int rb_ = w * 16 + i * 8;                                              \
      int r_ = rb_ + (lane >> 3);                                            \
      int sb_ = (lane & 7) ^ (r_ & 7);                                       \
      gload16(kbase + (size_t)((cc) * 64 + r_) * 128 + (sb_ << 3),           \
              KsL + (buf) * 4096 + rb_ * 64);                                \
    }                                                                        \
    _Pragma("unroll") for (int i = 0; i < 4; ++i) {                          \
      int rb_ = w * 16 + i * 4;                                              \
      int r_ = rb_ + (lane >> 4);                                            \
      int sb_ = (lane & 15) ^ (r_ & 7);                                      \
      gload16(vbase + (size_t)r_ * 512 + ((sb_ >> 3) << 8) + (cc) * 64 +     \
                  ((sb_ & 7) << 3),                                          \
              VtL + (buf) * 8192 + rb_ * 128);                               \
    }                                                                        \
  }

  STAGE_A(0, 0);
  __syncthreads();

  for (int c = 0; c < 4; ++c) {
    int buf = c & 1;
    if (c < 3) STAGE_A(c + 1, buf ^ 1);
    const ushort* Ks = KsL + buf * 4096;
    const ushort* Vs = VtL + buf * 8192;

    // S^T = Khi*Qhi + Khi*Qlo (2-term)
    f32x4 accS[2][4];
#pragma unroll
    for (int set = 0; set < 2; ++set)
#pragma unroll
      for (int t = 0; t < 4; ++t) accS[set][t] = (f32x4){0.f, 0.f, 0.f, 0.f};
#pragma unroll
    for (int kb = 0; kb < 2; ++kb) {
      bf16x8 ak[4];
#pragma unroll
      for (int t = 0; t < 4; ++t) {
        int kkr = t * 16 + q15;
        ak[t] = *(const bf16x8*)&Ks[kkr * 64 + (((kb * 4 + g) ^ (kkr & 7)) << 3)];
      }
#pragma unroll
      for (int set = 0; set < 2; ++set) {
#pragma unroll
        for (int t = 0; t < 4; ++t)
          accS[set][t] = __builtin_amdgcn_mfma_f32_16x16x32_bf16(
              ak[t], qf[set][0][kb], accS[set][t], 0, 0, 0);
#pragma unroll
        for (int t = 0; t < 4; ++t)
          accS[set][t] = __builtin_amdgcn_mfma_f32_16x16x32_bf16(
              ak[t], qf[set][1][kb], accS[set][t], 0, 0, 0);
      }
    }

#pragma unroll
    for (int set = 0; set < 2; ++set) {
      int qrowL = set * 64 + w * 16 + q15;
      float mx = -1e30f;
#pragma unroll
      for (int t = 0; t < 4; ++t)
#pragma unroll
        for (int r = 0; r < 4; ++r) mx = fmaxf(mx, accS[set][t][r]);
      mx = fmaxf(mx, __shfl_xor(mx, 16));
      mx = fmaxf(mx, __shfl_xor(mx, 32));
      float mn = fmaxf(m[set], mx);
      float fac = __expf(m[set] - mn);
      m[set] = mn;
      float sum = 0.f;
      ushort ph[4][4];
#pragma unroll
      for (int t = 0; t < 4; ++t)
#pragma unroll
        for (int r = 0; r < 4; ++r) {
          float p = __expf(accS[set][t][r] - mn);
          ushort hp = f2bf(p);
          ph[t][r] = hp;
          sum += bf2f(hp);
        }
      sum += __shfl_xor(sum, 16);
      sum += __shfl_xor(sum, 32);
      l[set] = l[set] * fac + sum;
#pragma unroll
      for (int t = 0; t < 4; ++t) {
        accO[set][t][0] *= fac; accO[set][t][1] *= fac;
        accO[set][t][2] *= fac; accO[set][t][3] *= fac;
      }
#pragma unroll
      for (int t = 0; t < 4; ++t)
#pragma unroll
        for (int rp = 0; rp < 4; rp += 2) {
          uint u = ph[t][rp] | ((uint)ph[t][rp + 1] << 16);
          int kkl = t * 16 + g * 4 + rp;
          int blk = kkl >> 3, off = kkl & 7;
          *(uint*)((char*)PL + qrowL * 128 + ((blk ^ (q15 & 7)) << 4) + off * 2) = u;
        }
    }
    __syncthreads();

    bf16x8 pf[2][2];
#pragma unroll
    for (int set = 0; set < 2; ++set) {
      int qrowL = set * 64 + w * 16 + q15;
#pragma unroll
      for (int kb = 0; kb < 2; ++kb)
        pf[set][kb] = *(const bf16x8*)((char*)PL + qrowL * 128 +
                                       (((kb * 4 + g) ^ (q15 & 7)) << 4));
    }
#pragma unroll
    for (int s = 0; s < 2; ++s)
#pragma unroll
      for (int kb = 0; kb < 2; ++kb)
#pragma unroll
        for (int t = 0; t < 4; ++t) {
          int d = t * 16 + q15;
          bf16x8 vf =
              *(const bf16x8*)&Vs[d * 128 + (((s * 8 + kb * 4 + g) ^ (d & 7)) << 3)];
          accO[0][t] = __builtin_amdgcn_mfma_f32_16x16x32_bf16(vf, pf[0][kb],
                                                               accO[0][t], 0, 0, 0);
          accO[1][t] = __builtin_amdgcn_mfma_f32_16x16x32_bf16(vf, pf[1][kb],
                                                               accO[1][t], 0, 0, 0);
        }
    __syncthreads();
  }
#undef STAGE_A

#pragma unroll
  for (int set = 0; set < 2; ++set) {
    if (set) __syncthreads();
    float inv = 1.0f / l[set];
#pragma unroll
    for (int t = 0; t < 4; ++t)
#pragma unroll
      for (int r = 0; r < 4; ++r)
        ob[(t * 16 + g * 4 + r) * 68 + w * 16 + q15] = accO[set][t][r] * inv;
    __syncthreads();
#pragma unroll
    for (int i = 0; i < 2; ++i) {
      int idx = tid + i * 256;
      int qq = idx >> 3, d8 = (idx & 7) << 3;
      ushort hh[8], ll[8];
#pragma unroll
      for (int jj = 0; jj < 8; ++jj) {
        float v = ob[(d8 + jj) * 68 + qq];
        hh[jj] = f2bf(v);
        ll[jj] = f2bf(v - bf2f(hh[jj]));
      }
      uint4 hp, lp;
      hp.x = hh[0] | ((uint)hh[1] << 16); hp.y = hh[2] | ((uint)hh[3] << 16);
      hp.z = hh[4] | ((uint)hh[5] << 16); hp.w = hh[6] | ((uint)hh[7] << 16);
      lp.x = ll[0] | ((uint)ll[1] << 16); lp.y = ll[2] | ((uint)ll[3] << 16);
      lp.z = ll[4] | ((uint)ll[5] << 16); lp.w = ll[6] | ((uint)ll[7] << 16);
      size_t rowb = (size_t)(b * 4096 + n0 + set * 64 + qq) * 1024 + h * 64 + d8;
      *(uint4*)(attno + rowb) = hp;
      *(uint4*)(attno + rowb + 512) = lp;
    }
  }
}

// ---------------- launch ----------------
extern "C" void kernel_launch(void* const* d_in, const int* in_sizes, int n_in,
                              void* d_out, int out_size, void* d_ws, size_t ws_size,
                              hipStream_t stream) {
  const float* x     = (const float*)d_in[0];
  const float* Wq    = (const float*)d_in[1];
  const float* bq    = (const float*)d_in[2];
  const float* Wk    = (const float*)d_in[3];
  const float* bk    = (const float*)d_in[4];
  const float* Wv    = (const float*)d_in[5];
  const float* bv    = (const float*)d_in[6];
  const float* Wp    = (const float*)d_in[7];
  const float* bp    = (const float*)d_in[8];
  const float* Wsr   = (const float*)d_in[9];
  const float* bsr   = (const float*)d_in[10];
  const float* gamma = (const float*)d_in[11];
  const float* beta  = (const float*)d_in[12];

  float* ws = (float*)d_ws;
  // bigws: xq/attno 8.39M | conv_part 8.39M | Qsplit 8.39M | Wsr_ 2.10M | rest 2.62M
  //   end = 29,885,440 fl = 119,541,760 B.
  bool bigws = ws_size >= 119541760ull;

  ushort* xq     = (ushort*)ws;
  ushort* attno_ = (ushort*)ws;
  float*  conv_part = ws + 8388608;             // [16][1024][512] f32 = 8,388,608 fl
  ushort* Qsplit = bigws ? (ushort*)(ws + 16777216)
                         : (ushort*)(ws + 8388608);   // compact: aliases conv_part
  size_t tail = bigws ? 25165824 : 16777216;
  ushort* Wsr_ = (ushort*)(ws + tail);          // hi-only: 4,194,304 us = 2,097,152 fl
  float*  rest = ws + tail + 2097152;
  ushort* Wq_  = (ushort*)rest;                 // 524,288 us = 262,144 fl
  ushort* Wp_  = (ushort*)(rest + 262144);      // 524,288 us = 262,144 fl
  ushort* Wkv_ = (ushort*)(rest + 524288);      // 1,048,576 us = 524,288 fl
  ushort* xkv_ = (ushort*)(rest + 1048576);     // 1,048,576 us = 524,288 fl
  ushort* Kq   = (ushort*)(rest + 1572864);     // 1,048,576 us = 524,288 fl
  ushort* Vt   = (ushort*)(rest + 2097152);     // 1,048,576 us = 524,288 fl
  float*  bkv  = rest + 2621440;                // 1,024 fl
  float* outp = (float*)d_out;

  prep_kernel<<<8705, 256, 0, stream>>>(x, Wq, Wp, Wk, Wv, Wsr, bk, bv,
                                        xq, Wq_, Wp_, Wkv_, Wsr_, bkv);
  if (bigws) {
    // conv (512 ids, 16 steps) + q-proj (512 ids, 16 steps) — uniform
    cq_kernel<<<1024, 256, 0, stream>>>(xq, Wsr_, conv_part, Wq_, bq, Qsplit, 0);
    ln_kernel<<<1024, 256, 0, stream>>>(conv_part, bsr, gamma, beta, xkv_);
  } else {
    cq_kernel<<<512, 256, 0, stream>>>(xq, Wsr_, conv_part, Wq_, bq, Qsplit, 0);
    ln_kernel<<<1024, 256, 0, stream>>>(conv_part, bsr, gamma, beta, xkv_);
    cq_kernel<<<512, 256, 0, stream>>>(xq, Wsr_, conv_part, Wq_, bq, Qsplit, 512);
  }
  kvproj_kernel<<<64, 256, 0, stream>>>(xkv_, Wkv_, bkv, Kq, Vt);
  attn_kernel<<<dim3(32, 8, 4), 256, 0, stream>>>(Qsplit, Kq, Vt, attno_);
  gemm_out_kernel<<<512, 256, 0, stream>>>(attno_, Wp_, bp, outp);
}

// Round 15
// 138.970 us; speedup vs baseline: 1.2528x; 1.1345x over previous
//
#include <hip/hip_runtime.h>

// B=4, H=W=64, N=4096, C=512, HEAD=8, dh=64, SR=4, Nk=256
// Split-bf16: val = hi + lo (both bf16).
// TERMS=3: aH*bH + aL*bH + aH*bL — kv-proj only.
// TERMS=2: aH*bH + aL*bH — conv, q-proj, out-proj.
// attn QK: 2-term (Khi*Qhi + Khi*Qlo); PV keeps Vhi+Vlo.
// LESSON r13: mixed-length blocks must be EXPLICITLY spread across XCDs and
// queued long-first — xcd_swz alone concentrates contiguous ids per XCD.

typedef __bf16 bf16x8 __attribute__((ext_vector_type(8)));
typedef float f32x4 __attribute__((ext_vector_type(4)));

__device__ __forceinline__ ushort f2bf(float v) {
  uint u = __float_as_uint(v);
  return (ushort)((u + 0x7FFFu + ((u >> 16) & 1u)) >> 16);
}
__device__ __forceinline__ float bf2f(ushort h) {
  return __uint_as_float((uint)h << 16);
}
__device__ __forceinline__ void gload16(const void* g, void* l) {
  __builtin_amdgcn_global_load_lds(
      (const __attribute__((address_space(1))) void*)g,
      (__attribute__((address_space(3))) void*)l, 16, 0, 0);
}
// bijective XCD swizzle for nwg % 8 == 0
__device__ __forceinline__ int xcd_swz(int bid, int nwg) {
  int cpx = nwg >> 3;
  return (bid & 7) * cpx + (bid >> 3);
}

// ---------------- fused prep: convert x, W's, Wsr(hi-only), biases ----------------
__global__ __launch_bounds__(256) void prep_kernel(
    const float* __restrict__ x, const float* __restrict__ Wq,
    const float* __restrict__ Wp, const float* __restrict__ Wk,
    const float* __restrict__ Wv, const float* __restrict__ Wsr,
    const float* __restrict__ bk, const float* __restrict__ bv,
    ushort* __restrict__ xq, ushort* __restrict__ Wq_,
    ushort* __restrict__ Wp_, ushort* __restrict__ Wkv_,
    ushort* __restrict__ Wsr_, float* __restrict__ bkv) {
  __shared__ float t[32][33];
  int bid = blockIdx.x, tid = threadIdx.x;
  if (bid < 4096 + 512) {
    const float* src;
    ushort* dst;
    int gid;
    bool need_lo = true;
    if (bid < 4096) {
      src = x; dst = xq; gid = bid * 256 + tid;
    } else {
      int z = (bid - 4096) >> 7;
      src = (z == 0) ? Wq : (z == 1) ? Wp : (z == 2) ? Wk : Wv;
      dst = (z == 0) ? Wq_ : (z == 1) ? Wp_ : (z == 2) ? Wkv_ : (Wkv_ + 512 * 1024);
      gid = ((bid - 4096) & 127) * 256 + tid;
      need_lo = (z >= 2);  // Wq_/Wp_ lo halves never read (TERMS=2 B-side)
    }
    int row = gid >> 6, c8 = (gid & 63) << 3;
    float4 a = *(const float4*)(src + (size_t)row * 512 + c8);
    float4 b = *(const float4*)(src + (size_t)row * 512 + c8 + 4);
    ushort h[8], l[8];
    float vv[8] = {a.x, a.y, a.z, a.w, b.x, b.y, b.z, b.w};
#pragma unroll
    for (int e = 0; e < 8; ++e) { h[e] = f2bf(vv[e]); l[e] = f2bf(vv[e] - bf2f(h[e])); }
    uint4 hp, lp;
    hp.x = h[0] | ((uint)h[1] << 16); hp.y = h[2] | ((uint)h[3] << 16);
    hp.z = h[4] | ((uint)h[5] << 16); hp.w = h[6] | ((uint)h[7] << 16);
    lp.x = l[0] | ((uint)l[1] << 16); lp.y = l[2] | ((uint)l[3] << 16);
    lp.z = l[4] | ((uint)l[5] << 16); lp.w = l[6] | ((uint)l[7] << 16);
    *(uint4*)(dst + (size_t)row * 1024 + c8) = hp;
    if (need_lo) *(uint4*)(dst + (size_t)row * 1024 + 512 + c8) = lp;
  } else if (bid < 4096 + 512 + 4096) {
    int tb = bid - 4608;
    int z = tb >> 8, rem = tb & 255;
    int ci0 = (rem >> 4) << 5, co0 = (rem & 15) << 5;
    int tx = tid & 31, ty = tid >> 5;
#pragma unroll
    for (int i = 0; i < 32; i += 8)
      t[ty + i][tx] = Wsr[((size_t)z * 512 + ci0 + ty + i) * 512 + co0 + tx];
    __syncthreads();
#pragma unroll
    for (int i = 0; i < 32; i += 8) {
      float v = t[tx][ty + i];
      int co = co0 + ty + i, ci = ci0 + tx;
      Wsr_[((size_t)z * 512 + co) * 512 + ci] = f2bf(v);  // hi only, stride 512
    }
  } else {
    bkv[tid] = bk[tid]; bkv[tid + 256] = bk[tid + 256];
    bkv[tid + 512] = bv[tid]; bkv[tid + 768] = bv[tid + 256];
  }
}

// ---------------- MFMA GEMM body: double-buffered 2-phase K-loop ----------------
// TERMS=3 -> 24 K-steps (K'=1536); TERMS=2 -> 16 K-steps (K'=1024).
//   ap = kk - (kk>=1024?1024:0)  -> A: hi, lo, [hi]
//   bp = kk - (kk>=512?512:0)    -> B: hi, hi, [lo]
// EPI=0: C fp32 + bias. EPI=1: Qsplit layout (LDS-coalesced). EPI=2: Kq/Vt scatter.
template <int EPI, int TERMS>
__device__ __forceinline__ void gemm_body(
    const ushort* __restrict__ A, const ushort* __restrict__ Bw,
    const float* __restrict__ bias, float* __restrict__ C,
    ushort* __restrict__ Qs, ushort* __restrict__ Kq, ushort* __restrict__ Vt,
    int N, int bx, int by, ushort* lds) {
  constexpr int NS = TERMS * 8;  // K-steps
  int tid = threadIdx.x;
  int lane = tid & 63, w = tid >> 6;
  int wr = w >> 1, wc = w & 1;
  int l15 = lane & 15, g = lane >> 4;
  int srow = lane >> 3;
  int scol = (lane & 7) ^ srow;

  const ushort* aBase = A + (size_t)(by * 128 + w * 32 + srow) * 1024 + scol * 8;
  const ushort* bBase = Bw + (size_t)(bx * 128 + w * 32 + srow) * 1024 + scol * 8;

  f32x4 acc[4][4];
#pragma unroll
  for (int i = 0; i < 4; ++i)
#pragma unroll
    for (int j = 0; j < 4; ++j) acc[i][j] = (f32x4){0.f, 0.f, 0.f, 0.f};

#define STAGE_G(ks, buf)                                              \
  {                                                                   \
    int kk = (ks) * 64;                                               \
    int ap = kk - (kk >= 1024 ? 1024 : 0);                            \
    int bp = kk - (kk >= 512 ? 512 : 0);                              \
    ushort* aD = lds + (buf) * 16384 + w * 2048;                      \
    ushort* bD = lds + (buf) * 16384 + 8192 + w * 2048;               \
    _Pragma("unroll") for (int t = 0; t < 4; ++t) {                   \
      gload16(aBase + (size_t)t * 8192 + ap, aD + t * 512);           \
      gload16(bBase + (size_t)t * 8192 + bp, bD + t * 512);           \
    }                                                                 \
  }

#define COMPUTE_G(buf)                                                         \
  {                                                                            \
    const ushort* As = lds + (buf) * 16384;                                    \
    const ushort* Bs = As + 8192;                                              \
    _Pragma("unroll") for (int kk2 = 0; kk2 < 2; ++kk2) {                      \
      int rb = kk2 * 4 + g;                                                    \
      bf16x8 af[4], bg[4];                                                     \
      _Pragma("unroll") for (int i = 0; i < 4; ++i) {                          \
        int row = wr * 64 + i * 16 + l15;                                      \
        af[i] = *(const bf16x8*)&As[row * 64 + ((rb ^ (row & 7)) << 3)];       \
      }                                                                        \
      _Pragma("unroll") for (int j = 0; j < 4; ++j) {                          \
        int col = wc * 64 + j * 16 + l15;                                      \
        bg[j] = *(const bf16x8*)&Bs[col * 64 + ((rb ^ (col & 7)) << 3)];       \
      }                                                                        \
      _Pragma("unroll") for (int i = 0; i < 4; ++i)                            \
        _Pragma("unroll") for (int j = 0; j < 4; ++j)                          \
          acc[i][j] =                                                          \
              __builtin_amdgcn_mfma_f32_16x16x32_bf16(af[i], bg[j], acc[i][j], \
                                                      0, 0, 0);                \
    }                                                                          \
  }

  STAGE_G(0, 0);
  __syncthreads();
  for (int ks = 0; ks < NS - 1; ++ks) {
    STAGE_G(ks + 1, (ks + 1) & 1);
    COMPUTE_G(ks & 1);
    __syncthreads();
  }
  COMPUTE_G((NS - 1) & 1);

#undef STAGE_G
#undef COMPUTE_G

  if (EPI == 0) {
#pragma unroll
    for (int j = 0; j < 4; ++j) {
      int col = bx * 128 + wc * 64 + j * 16 + l15;
      float bj = bias ? bias[col] : 0.f;
#pragma unroll
      for (int i = 0; i < 4; ++i) {
        int row0 = by * 128 + wr * 64 + i * 16 + g * 4;
#pragma unroll
        for (int r = 0; r < 4; ++r)
          C[(size_t)(row0 + r) * N + col] = acc[i][j][r] + bj;
      }
    }
  } else if (EPI == 1) {
    __syncthreads();
#pragma unroll
    for (int j = 0; j < 4; ++j) {
      int cl = wc * 64 + j * 16 + l15;
      float bj = bias[bx * 128 + cl];
#pragma unroll
      for (int i = 0; i < 4; ++i) {
        int rl0 = wr * 64 + i * 16 + g * 4;
#pragma unroll
        for (int r = 0; r < 4; ++r) {
          float v = (acc[i][j][r] + bj) * 0.125f;
          ushort h = f2bf(v), lo = f2bf(v - bf2f(h));
          lds[(rl0 + r) * 128 + cl] = h;
          lds[16384 + (rl0 + r) * 128 + cl] = lo;
        }
      }
    }
    __syncthreads();
#pragma unroll
    for (int it = 0; it < 8; ++it) {
      int c = tid + it * 256;
      int r = c >> 4, ck = c & 15;
      int grow = by * 128 + r;
      size_t base = ((size_t)grow * 8 + bx * 2 + (ck >> 3)) * 128 + (ck & 7) * 8;
      *(uint4*)(Qs + base) = *(const uint4*)&lds[r * 128 + ck * 8];
      *(uint4*)(Qs + base + 64) = *(const uint4*)&lds[16384 + r * 128 + ck * 8];
    }
  } else {
    // EPI=2: kv epilogue — scatter split-bf16 directly into Kq / Vt layouts.
#pragma unroll
    for (int j = 0; j < 4; ++j) {
      int col = bx * 128 + wc * 64 + j * 16 + l15;
      float bj = bias[col];
      bool isK = col < 512;
      int cp = isK ? col : col - 512;
      int hh = cp >> 6, d = cp & 63;
#pragma unroll
      for (int i = 0; i < 4; ++i) {
        int row0 = by * 128 + wr * 64 + i * 16 + g * 4;
#pragma unroll
        for (int r = 0; r < 4; ++r) {
          int row = row0 + r;
          int b = row >> 8, kk = row & 255;
          float v = acc[i][j][r] + bj;
          ushort h = f2bf(v), lo = f2bf(v - bf2f(h));
          if (isK) {
            size_t base = ((size_t)((b * 8 + hh) * 256) + kk) * 128 + d;
            Kq[base] = h; Kq[base + 64] = lo;
          } else {
            size_t base = ((size_t)((b * 8 + hh) * 64) + d) * 512 + kk;
            Vt[base] = h; Vt[base + 256] = lo;
          }
        }
      }
    }
  }
}

// ---------------- conv body: split-16 (ONE tap per block), TERMS=2, 16 steps ----------
// Wsr_ hi-only [16 taps][512 co][512 ci]. x full split: ap = kk in [0,1024).
__device__ __forceinline__ void conv_body(
    const ushort* __restrict__ xq, const ushort* __restrict__ Wsr_,
    float* __restrict__ part, int bx, int by, int z, ushort* lds) {
  int kh = z >> 2, kw = z & 3;
  int tid = threadIdx.x;
  int lane = tid & 63, w = tid >> 6;
  int wr = w >> 1, wc = w & 1;
  int l15 = lane & 15, g = lane >> 4;
  int srow = lane >> 3;
  int scol = (lane & 7) ^ srow;

  const ushort* aBase[4];
#pragma unroll
  for (int t = 0; t < 4; ++t) {
    int gm = by * 128 + w * 32 + t * 8 + srow;
    int xr = (gm >> 8) * 4096 + ((((gm >> 4) & 15) << 2) + kh) * 64 +
             ((gm & 15) << 2) + kw;
    aBase[t] = xq + (size_t)xr * 1024 + scol * 8;
  }
  const ushort* bBase =
      Wsr_ + ((size_t)(z * 512 + bx * 128 + w * 32 + srow)) * 512 + scol * 8;

  f32x4 acc[4][4];
#pragma unroll
  for (int i = 0; i < 4; ++i)
#pragma unroll
    for (int j = 0; j < 4; ++j) acc[i][j] = (f32x4){0.f, 0.f, 0.f, 0.f};

#define STAGE_C(ks, buf)                                              \
  {                                                                   \
    int kk = (ks) * 64;                                               \
    int bp = kk - (kk >= 512 ? 512 : 0);                              \
    ushort* aD = lds + (buf) * 16384 + w * 2048;                      \
    ushort* bD = lds + (buf) * 16384 + 8192 + w * 2048;               \
    _Pragma("unroll") for (int t = 0; t < 4; ++t) {                   \
      gload16(aBase[t] + kk, aD + t * 512);                           \
      gload16(bBase + (size_t)t * 4096 + bp, bD + t * 512);           \
    }                                                                 \
  }

#define COMPUTE_C(buf)                                                         \
  {                                                                            \
    const ushort* As = lds + (buf) * 16384;                                    \
    const ushort* Bs = As + 8192;                                              \
    _Pragma("unroll") for (int kk2 = 0; kk2 < 2; ++kk2) {                      \
      int rb = kk2 * 4 + g;                                                    \
      bf16x8 af[4], bg[4];                                                     \
      _Pragma("unroll") for (int i = 0; i < 4; ++i) {                          \
        int row = wr * 64 + i * 16 + l15;                                      \
        af[i] = *(const bf16x8*)&As[row * 64 + ((rb ^ (row & 7)) << 3)];       \
      }                                                                        \
      _Pragma("unroll") for (int j = 0; j < 4; ++j) {                          \
        int col = wc * 64 + j * 16 + l15;                                      \
        bg[j] = *(const bf16x8*)&Bs[col * 64 + ((rb ^ (col & 7)) << 3)];       \
      }                                                                        \
      _Pragma("unroll") for (int i = 0; i < 4; ++i)                            \
        _Pragma("unroll") for (int j = 0; j < 4; ++j)                          \
          acc[i][j] =                                                          \
              __builtin_amdgcn_mfma_f32_16x16x32_bf16(af[i], bg[j], acc[i][j], \
                                                      0, 0, 0);                \
    }                                                                          \
  }

  STAGE_C(0, 0);
  __syncthreads();
  for (int ks = 0; ks < 15; ++ks) {
    STAGE_C(ks + 1, (ks + 1) & 1);
    COMPUTE_C(ks & 1);
    __syncthreads();
  }
  COMPUTE_C(1);

#undef STAGE_C
#undef COMPUTE_C

  float* Cp = part + (size_t)z * 524288;
#pragma unroll
  for (int j = 0; j < 4; ++j) {
    int col = bx * 128 + wc * 64 + j * 16 + l15;
#pragma unroll
    for (int i = 0; i < 4; ++i) {
      int row0 = by * 128 + wr * 64 + i * 16 + g * 4;
#pragma unroll
      for (int r = 0; r < 4; ++r)
        Cp[(size_t)(row0 + r) * 512 + col] = acc[i][j][r];
    }
  }
}

// conv only: 512 blocks, uniform 16 steps
__global__ __launch_bounds__(256) void conv_kernel(
    const ushort* __restrict__ xq, const ushort* __restrict__ Wsr_,
    float* __restrict__ part) {
  __shared__ __align__(16) ushort lds[32768];
  int bid = xcd_swz(blockIdx.x, 512);
  conv_body(xq, Wsr_, part, bid & 3, (bid >> 2) & 7, bid >> 5, lds);
}

// q-proj (512 x 16-step) + kv-proj (64 x 24-step) in one launch.
// Explicit mapping: xcd = n&7 (hardware round-robin), slot = n>>3.
// slot<8 -> kvproj (8 long blocks per XCD, queued FIRST); else q-proj.
__global__ __launch_bounds__(256) void qkv_kernel(
    const ushort* __restrict__ xq, const ushort* __restrict__ Wq_,
    const float* __restrict__ bq, ushort* __restrict__ Qs,
    const ushort* __restrict__ xkv_, const ushort* __restrict__ Wkv_,
    const float* __restrict__ bkv, ushort* __restrict__ Kq,
    ushort* __restrict__ Vt) {
  __shared__ __align__(16) ushort lds[32768];
  int n = blockIdx.x;  // 576
  int xcd = n & 7, slot = n >> 3;
  if (slot < 8) {
    int id = xcd * 8 + slot;  // 0..63
    gemm_body<2, 3>(xkv_, Wkv_, bkv, nullptr, nullptr, Kq, Vt, 1024,
                    id & 7, id >> 3, lds);
  } else {
    int id = xcd * 64 + (slot - 8);  // 0..511
    gemm_body<1, 2>(xq, Wq_, bq, nullptr, Qs, nullptr, nullptr, 512,
                    id & 3, id >> 2, lds);
  }
}

// out-proj (TERMS=2)
__global__ __launch_bounds__(256) void gemm_out_kernel(
    const ushort* __restrict__ A, const ushort* __restrict__ Bw,
    const float* __restrict__ bias, float* __restrict__ C) {
  __shared__ __align__(16) ushort lds[32768];
  int bid = xcd_swz(blockIdx.x, 512);
  gemm_body<0, 2>(A, Bw, bias, C, nullptr, nullptr, nullptr, 512,
                  bid & 3, bid >> 2, lds);
}

// ---------------- partial-sum(16) + bias + LayerNorm -> split-bf16 ----------------
__global__ __launch_bounds__(256) void ln_kernel(
    const float* __restrict__ part, const float* __restrict__ bsr,
    const float* __restrict__ gamma, const float* __restrict__ beta,
    ushort* __restrict__ xkv_) {
  int row = blockIdx.x;
  int t = threadIdx.x;
  float v0 = bsr[t], v1 = bsr[t + 256];
  for (int p = 0; p < 16; ++p) {
    v0 += part[(size_t)p * 524288 + (size_t)row * 512 + t];
    v1 += part[(size_t)p * 524288 + (size_t)row * 512 + t + 256];
  }
  float s = v0 + v1, sq = v0 * v0 + v1 * v1;
#pragma unroll
  for (int o = 1; o < 64; o <<= 1) {
    s += __shfl_xor(s, o);
    sq += __shfl_xor(sq, o);
  }
  __shared__ float red[8];
  int wv = t >> 6;
  if ((t & 63) == 0) { red[wv] = s; red[4 + wv] = sq; }
  __syncthreads();
  s = red[0] + red[1] + red[2] + red[3];
  sq = red[4] + red[5] + red[6] + red[7];
  float mu = s * (1.0f / 512.0f);
  float var = sq * (1.0f / 512.0f) - mu * mu;
  float rs = rsqrtf(var + 1e-5f);
  float y0 = (v0 - mu) * rs * gamma[t] + beta[t];
  float y1 = (v1 - mu) * rs * gamma[t + 256] + beta[t + 256];
  ushort h0 = f2bf(y0), h1 = f2bf(y1);
  xkv_[(size_t)row * 1024 + t] = h0;
  xkv_[(size_t)row * 1024 + t + 256] = h1;
  xkv_[(size_t)row * 1024 + 512 + t] = f2bf(y0 - bf2f(h0));
  xkv_[(size_t)row * 1024 + 512 + t + 256] = f2bf(y1 - bf2f(h1));
}

// ---------------- MFMA flash attention: 128 q/block, QK 2-term, dbuf DMA ----------------
__global__ __launch_bounds__(256, 2) void attn_kernel(
    const ushort* __restrict__ Qs, const ushort* __restrict__ Kq,
    const ushort* __restrict__ Vt, ushort* __restrict__ attno) {
  __shared__ __align__(16) char arena[65536];
  ushort* KsL = (ushort*)arena;            // [2][64 kk][64 hi], swizzled (8KB/buf)
  ushort* VtL = (ushort*)(arena + 16384);  // [2][64 d][128 hi|lo kk] (16KB/buf)
  ushort* PL = (ushort*)(arena + 49152);   // [128 q][64 kk] bf16, swizzled
  float* ob = (float*)arena;               // epilogue alias

  int tid = threadIdx.x;
  int qb = blockIdx.x, h = blockIdx.y, b = blockIdx.z;
  int n0 = qb * 128, bh = b * 8 + h;
  int lane = tid & 63, w = tid >> 6;
  int q15 = lane & 15, g = lane >> 4;

  const ushort* kbase = Kq + (size_t)bh * 256 * 128;
  const ushort* vbase = Vt + (size_t)bh * 64 * 512;

  bf16x8 qf[2][2][2];
#pragma unroll
  for (int set = 0; set < 2; ++set) {
    const ushort* qptr =
        Qs + ((size_t)(b * 4096 + n0 + set * 64 + w * 16 + q15) * 8 + h) * 128;
#pragma unroll
    for (int s = 0; s < 2; ++s)
#pragma unroll
      for (int kb = 0; kb < 2; ++kb)
        qf[set][s][kb] = *(const bf16x8*)(qptr + s * 64 + kb * 32 + g * 8);
  }

  f32x4 accO[2][4];
#pragma unroll
  for (int set = 0; set < 2; ++set)
#pragma unroll
    for (int t = 0; t < 4; ++t) accO[set][t] = (f32x4){0.f, 0.f, 0.f, 0.f};
  float m[2] = {-1e30f, -1e30f}, l[2] = {0.f, 0.f};

#define STAGE_A(cc, buf)                                                     \
  {                                                                          \
    _Pragma("unroll") for (int i = 0; i < 2; ++i) {                          \
      int rb_ = w * 16 + i * 8;                                              \
      int r_ = rb_ + (lane >> 3);                                            \
      int sb_ = (lane & 7) ^ (r_ & 7);                                       \
      gload16(kbase + (size_t)((cc) * 64 + r_) * 128 + (sb_ << 3),           \
              KsL + (buf) * 4096 + rb_ * 64);                                \
    }                                                                        \
    _Pragma("unroll") for (int i = 0; i < 4; ++i) {                          \
      int rb_ = w * 16 + i * 4;                                              \
      int r_ = rb_ + (lane >> 4);                                            \
      int sb_ = (lane & 15) ^ (r_ & 7);                                      \
      gload16(vbase + (size_t)r_ * 512 + ((sb_ >> 3) << 8) + (cc) * 64 +     \
                  ((sb_ & 7) << 3),                                          \
              VtL + (buf) * 8192 + rb_ * 128);                               \
    }                                                                        \
  }

  STAGE_A(0, 0);
  __syncthreads();

  for (int c = 0; c < 4; ++c) {
    int buf = c & 1;
    if (c < 3) STAGE_A(c + 1, buf ^ 1);
    const ushort* Ks = KsL + buf * 4096;
    const ushort* Vs = VtL + buf * 8192;

    // S^T = Khi*Qhi + Khi*Qlo (2-term)
    f32x4 accS[2][4];
#pragma unroll
    for (int set = 0; set < 2; ++set)
#pragma unroll
      for (int t = 0; t < 4; ++t) accS[set][t] = (f32x4){0.f, 0.f, 0.f, 0.f};
#pragma unroll
    for (int kb = 0; kb < 2; ++kb) {
      bf16x8 ak[4];
#pragma unroll
      for (int t = 0; t < 4; ++t) {
        int kkr = t * 16 + q15;
        ak[t] = *(const bf16x8*)&Ks[kkr * 64 + (((kb * 4 + g) ^ (kkr & 7)) << 3)];
      }
#pragma unroll
      for (int set = 0; set < 2; ++set) {
#pragma unroll
        for (int t = 0; t < 4; ++t)
          accS[set][t] = __builtin_amdgcn_mfma_f32_16x16x32_bf16(
              ak[t], qf[set][0][kb], accS[set][t], 0, 0, 0);
#pragma unroll
        for (int t = 0; t < 4; ++t)
          accS[set][t] = __builtin_amdgcn_mfma_f32_16x16x32_bf16(
              ak[t], qf[set][1][kb], accS[set][t], 0, 0, 0);
      }
    }

#pragma unroll
    for (int set = 0; set < 2; ++set) {
      int qrowL = set * 64 + w * 16 + q15;
      float mx = -1e30f;
#pragma unroll
      for (int t = 0; t < 4; ++t)
#pragma unroll
        for (int r = 0; r < 4; ++r) mx = fmaxf(mx, accS[set][t][r]);
      mx = fmaxf(mx, __shfl_xor(mx, 16));
      mx = fmaxf(mx, __shfl_xor(mx, 32));
      float mn = fmaxf(m[set], mx);
      float fac = __expf(m[set] - mn);
      m[set] = mn;
      float sum = 0.f;
      ushort ph[4][4];
#pragma unroll
      for (int t = 0; t < 4; ++t)
#pragma unroll
        for (int r = 0; r < 4; ++r) {
          float p = __expf(accS[set][t][r] - mn);
          ushort hp = f2bf(p);
          ph[t][r] = hp;
          sum += bf2f(hp);
        }
      sum += __shfl_xor(sum, 16);
      sum += __shfl_xor(sum, 32);
      l[set] = l[set] * fac + sum;
#pragma unroll
      for (int t = 0; t < 4; ++t) {
        accO[set][t][0] *= fac; accO[set][t][1] *= fac;
        accO[set][t][2] *= fac; accO[set][t][3] *= fac;
      }
#pragma unroll
      for (int t = 0; t < 4; ++t)
#pragma unroll
        for (int rp = 0; rp < 4; rp += 2) {
          uint u = ph[t][rp] | ((uint)ph[t][rp + 1] << 16);
          int kkl = t * 16 + g * 4 + rp;
          int blk = kkl >> 3, off = kkl & 7;
          *(uint*)((char*)PL + qrowL * 128 + ((blk ^ (q15 & 7)) << 4) + off * 2) = u;
        }
    }
    __syncthreads();

    bf16x8 pf[2][2];
#pragma unroll
    for (int set = 0; set < 2; ++set) {
      int qrowL = set * 64 + w * 16 + q15;
#pragma unroll
      for (int kb = 0; kb < 2; ++kb)
        pf[set][kb] = *(const bf16x8*)((char*)PL + qrowL * 128 +
                                       (((kb * 4 + g) ^ (q15 & 7)) << 4));
    }
#pragma unroll
    for (int s = 0; s < 2; ++s)
#pragma unroll
      for (int kb = 0; kb < 2; ++kb)
#pragma unroll
        for (int t = 0; t < 4; ++t) {
          int d = t * 16 + q15;
          bf16x8 vf =
              *(const bf16x8*)&Vs[d * 128 + (((s * 8 + kb * 4 + g) ^ (d & 7)) << 3)];
          accO[0][t] = __builtin_amdgcn_mfma_f32_16x16x32_bf16(vf, pf[0][kb],
                                                               accO[0][t], 0, 0, 0);
          accO[1][t] = __builtin_amdgcn_mfma_f32_16x16x32_bf16(vf, pf[1][kb],
                                                               accO[1][t], 0, 0, 0);
        }
    __syncthreads();
  }
#undef STAGE_A

#pragma unroll
  for (int set = 0; set < 2; ++set) {
    if (set) __syncthreads();
    float inv = 1.0f / l[set];
#pragma unroll
    for (int t = 0; t < 4; ++t)
#pragma unroll
      for (int r = 0; r < 4; ++r)
        ob[(t * 16 + g * 4 + r) * 68 + w * 16 + q15] = accO[set][t][r] * inv;
    __syncthreads();
#pragma unroll
    for (int i = 0; i < 2; ++i) {
      int idx = tid + i * 256;
      int qq = idx >> 3, d8 = (idx & 7) << 3;
      ushort hh[8], ll[8];
#pragma unroll
      for (int jj = 0; jj < 8; ++jj) {
        float v = ob[(d8 + jj) * 68 + qq];
        hh[jj] = f2bf(v);
        ll[jj] = f2bf(v - bf2f(hh[jj]));
      }
      uint4 hp, lp;
      hp.x = hh[0] | ((uint)hh[1] << 16); hp.y = hh[2] | ((uint)hh[3] << 16);
      hp.z = hh[4] | ((uint)hh[5] << 16); hp.w = hh[6] | ((uint)hh[7] << 16);
      lp.x = ll[0] | ((uint)ll[1] << 16); lp.y = ll[2] | ((uint)ll[3] << 16);
      lp.z = ll[4] | ((uint)ll[5] << 16); lp.w = ll[6] | ((uint)ll[7] << 16);
      size_t rowb = (size_t)(b * 4096 + n0 + set * 64 + qq) * 1024 + h * 64 + d8;
      *(uint4*)(attno + rowb) = hp;
      *(uint4*)(attno + rowb + 512) = lp;
    }
  }
}

// ---------------- launch ----------------
extern "C" void kernel_launch(void* const* d_in, const int* in_sizes, int n_in,
                              void* d_out, int out_size, void* d_ws, size_t ws_size,
                              hipStream_t stream) {
  const float* x     = (const float*)d_in[0];
  const float* Wq    = (const float*)d_in[1];
  const float* bq    = (const float*)d_in[2];
  const float* Wk    = (const float*)d_in[3];
  const float* bk    = (const float*)d_in[4];
  const float* Wv    = (const float*)d_in[5];
  const float* bv    = (const float*)d_in[6];
  const float* Wp    = (const float*)d_in[7];
  const float* bp    = (const float*)d_in[8];
  const float* Wsr   = (const float*)d_in[9];
  const float* bsr   = (const float*)d_in[10];
  const float* gamma = (const float*)d_in[11];
  const float* beta  = (const float*)d_in[12];

  float* ws = (float*)d_ws;
  // Single layout (qproj always after ln -> Qsplit aliases conv_part):
  // xq/attno 8.39M | conv_part/Qsplit 8.39M | Wsr_ 2.10M | rest 2.62M
  //   end = 21,496,832 fl = 85,987,328 B.
  ushort* xq     = (ushort*)ws;
  ushort* attno_ = (ushort*)ws;
  float*  conv_part = ws + 8388608;             // [16][1024][512] f32
  ushort* Qsplit = (ushort*)(ws + 8388608);     // aliases conv_part (after ln)
  ushort* Wsr_ = (ushort*)(ws + 16777216);      // hi-only: 4,194,304 us
  float*  rest = ws + 18874368;
  ushort* Wq_  = (ushort*)rest;                 // 524,288 us = 262,144 fl
  ushort* Wp_  = (ushort*)(rest + 262144);      // 524,288 us
  ushort* Wkv_ = (ushort*)(rest + 524288);      // 1,048,576 us
  ushort* xkv_ = (ushort*)(rest + 1048576);     // 1,048,576 us
  ushort* Kq   = (ushort*)(rest + 1572864);     // 1,048,576 us
  ushort* Vt   = (ushort*)(rest + 2097152);     // 1,048,576 us
  float*  bkv  = rest + 2621440;                // 1,024 fl
  float* outp = (float*)d_out;

  prep_kernel<<<8705, 256, 0, stream>>>(x, Wq, Wp, Wk, Wv, Wsr, bk, bv,
                                        xq, Wq_, Wp_, Wkv_, Wsr_, bkv);
  conv_kernel<<<512, 256, 0, stream>>>(xq, Wsr_, conv_part);
  ln_kernel<<<1024, 256, 0, stream>>>(conv_part, bsr, gamma, beta, xkv_);
  qkv_kernel<<<576, 256, 0, stream>>>(xq, Wq_, bq, Qsplit,
                                      xkv_, Wkv_, bkv, Kq, Vt);
  attn_kernel<<<dim3(32, 8, 4), 256, 0, stream>>>(Qsplit, Kq, Vt, attno_);
  gemm_out_kernel<<<512, 256, 0, stream>>>(attno_, Wp_, bp, outp);
}

// Round 16
// 120.068 us; speedup vs baseline: 1.4501x; 1.1574x over previous
//
#include <hip/hip_runtime.h>

// B=4, H=W=64, N=4096, C=512, HEAD=8, dh=64, SR=4, Nk=256
// Split-bf16 tiers (error budget validated empirically: absmax pinned at the
// 2.44e-4 bf16-ulp floor through three ~2e-3-magnitude term drops):
//   TERMS=3 (24 steps, full split both sides)  — kv-proj (K/V precision).
//   TERMS=1 (8 steps, pure bf16 hi*hi, K=512)  — conv, q-proj, out-proj.
//   attn: QK 2-term (Khi*Qhi + Khi*Qlo, Q split from fp32 acc); PV Vhi+Vlo.
// LESSON r13: mixed-length blocks must be explicitly spread long-first per XCD.

typedef __bf16 bf16x8 __attribute__((ext_vector_type(8)));
typedef float f32x4 __attribute__((ext_vector_type(4)));

__device__ __forceinline__ ushort f2bf(float v) {
  uint u = __float_as_uint(v);
  return (ushort)((u + 0x7FFFu + ((u >> 16) & 1u)) >> 16);
}
__device__ __forceinline__ float bf2f(ushort h) {
  return __uint_as_float((uint)h << 16);
}
__device__ __forceinline__ void gload16(const void* g, void* l) {
  __builtin_amdgcn_global_load_lds(
      (const __attribute__((address_space(1))) void*)g,
      (__attribute__((address_space(3))) void*)l, 16, 0, 0);
}
// bijective XCD swizzle for nwg % 8 == 0
__device__ __forceinline__ int xcd_swz(int bid, int nwg) {
  int cpx = nwg >> 3;
  return (bid & 7) * cpx + (bid >> 3);
}

// ---------------- fused prep ----------------
// x -> xq hi-only [16384][512]; Wq/Wp -> hi-only [512][512];
// Wk|Wv -> Wkv_ full split [1024][1024]; Wsr -> hi-only transposed; bkv concat.
__global__ __launch_bounds__(256) void prep_kernel(
    const float* __restrict__ x, const float* __restrict__ Wq,
    const float* __restrict__ Wp, const float* __restrict__ Wk,
    const float* __restrict__ Wv, const float* __restrict__ Wsr,
    const float* __restrict__ bk, const float* __restrict__ bv,
    ushort* __restrict__ xq, ushort* __restrict__ Wq_,
    ushort* __restrict__ Wp_, ushort* __restrict__ Wkv_,
    ushort* __restrict__ Wsr_, float* __restrict__ bkv) {
  __shared__ float t[32][33];
  int bid = blockIdx.x, tid = threadIdx.x;
  if (bid < 4096 + 512) {
    const float* src;
    ushort* dst;
    int gid;
    bool full = false;
    if (bid < 4096) {
      src = x; dst = xq; gid = bid * 256 + tid;
    } else {
      int z = (bid - 4096) >> 7;
      src = (z == 0) ? Wq : (z == 1) ? Wp : (z == 2) ? Wk : Wv;
      dst = (z == 0) ? Wq_ : (z == 1) ? Wp_ : (z == 2) ? Wkv_ : (Wkv_ + 512 * 1024);
      gid = ((bid - 4096) & 127) * 256 + tid;
      full = (z >= 2);  // only Wk/Wv need the lo half (TERMS=3 kv-proj)
    }
    int row = gid >> 6, c8 = (gid & 63) << 3;
    float4 a = *(const float4*)(src + (size_t)row * 512 + c8);
    float4 b = *(const float4*)(src + (size_t)row * 512 + c8 + 4);
    ushort h[8], l[8];
    float vv[8] = {a.x, a.y, a.z, a.w, b.x, b.y, b.z, b.w};
#pragma unroll
    for (int e = 0; e < 8; ++e) { h[e] = f2bf(vv[e]); l[e] = f2bf(vv[e] - bf2f(h[e])); }
    uint4 hp, lp;
    hp.x = h[0] | ((uint)h[1] << 16); hp.y = h[2] | ((uint)h[3] << 16);
    hp.z = h[4] | ((uint)h[5] << 16); hp.w = h[6] | ((uint)h[7] << 16);
    lp.x = l[0] | ((uint)l[1] << 16); lp.y = l[2] | ((uint)l[3] << 16);
    lp.z = l[4] | ((uint)l[5] << 16); lp.w = l[6] | ((uint)l[7] << 16);
    if (full) {
      *(uint4*)(dst + (size_t)row * 1024 + c8) = hp;
      *(uint4*)(dst + (size_t)row * 1024 + 512 + c8) = lp;
    } else {
      *(uint4*)(dst + (size_t)row * 512 + c8) = hp;
    }
  } else if (bid < 4096 + 512 + 4096) {
    int tb = bid - 4608;
    int z = tb >> 8, rem = tb & 255;
    int ci0 = (rem >> 4) << 5, co0 = (rem & 15) << 5;
    int tx = tid & 31, ty = tid >> 5;
#pragma unroll
    for (int i = 0; i < 32; i += 8)
      t[ty + i][tx] = Wsr[((size_t)z * 512 + ci0 + ty + i) * 512 + co0 + tx];
    __syncthreads();
#pragma unroll
    for (int i = 0; i < 32; i += 8) {
      float v = t[tx][ty + i];
      int co = co0 + ty + i, ci = ci0 + tx;
      Wsr_[((size_t)z * 512 + co) * 512 + ci] = f2bf(v);  // hi only
    }
  } else {
    bkv[tid] = bk[tid]; bkv[tid + 256] = bk[tid + 256];
    bkv[tid + 512] = bv[tid]; bkv[tid + 768] = bv[tid + 256];
  }
}

// ---------------- MFMA GEMM body: double-buffered 2-phase K-loop ----------------
// TERMS=1: 8 steps, A/B stride 512 (pure bf16). TERMS=3: 24 steps, stride 1024:
//   ap = kk - (kk>=1024?1024:0)  -> A: hi, lo, hi
//   bp = kk - (kk>=512?512:0)    -> B: hi, hi, lo
// EPI=0: C fp32 + bias. EPI=1: Qsplit layout (LDS-coalesced). EPI=2: Kq/Vt scatter.
template <int EPI, int TERMS>
__device__ __forceinline__ void gemm_body(
    const ushort* __restrict__ A, const ushort* __restrict__ Bw,
    const float* __restrict__ bias, float* __restrict__ C,
    ushort* __restrict__ Qs, ushort* __restrict__ Kq, ushort* __restrict__ Vt,
    int N, int bx, int by, ushort* lds) {
  constexpr int NS = (TERMS == 1) ? 8 : TERMS * 8;
  constexpr int AST = (TERMS == 1) ? 512 : 1024;
  int tid = threadIdx.x;
  int lane = tid & 63, w = tid >> 6;
  int wr = w >> 1, wc = w & 1;
  int l15 = lane & 15, g = lane >> 4;
  int srow = lane >> 3;
  int scol = (lane & 7) ^ srow;

  const ushort* aBase = A + (size_t)(by * 128 + w * 32 + srow) * AST + scol * 8;
  const ushort* bBase = Bw + (size_t)(bx * 128 + w * 32 + srow) * AST + scol * 8;

  f32x4 acc[4][4];
#pragma unroll
  for (int i = 0; i < 4; ++i)
#pragma unroll
    for (int j = 0; j < 4; ++j) acc[i][j] = (f32x4){0.f, 0.f, 0.f, 0.f};

#define STAGE_G(ks, buf)                                              \
  {                                                                   \
    int kk = (ks) * 64;                                               \
    int ap = (TERMS == 1) ? kk : kk - (kk >= 1024 ? 1024 : 0);        \
    int bp = (TERMS == 1) ? kk : kk - (kk >= 512 ? 512 : 0);          \
    ushort* aD = lds + (buf) * 16384 + w * 2048;                      \
    ushort* bD = lds + (buf) * 16384 + 8192 + w * 2048;               \
    _Pragma("unroll") for (int t = 0; t < 4; ++t) {                   \
      gload16(aBase + (size_t)t * 8 * AST + ap, aD + t * 512);        \
      gload16(bBase + (size_t)t * 8 * AST + bp, bD + t * 512);        \
    }                                                                 \
  }

#define COMPUTE_G(buf)                                                         \
  {                                                                            \
    const ushort* As = lds + (buf) * 16384;                                    \
    const ushort* Bs = As + 8192;                                              \
    _Pragma("unroll") for (int kk2 = 0; kk2 < 2; ++kk2) {                      \
      int rb = kk2 * 4 + g;                                                    \
      bf16x8 af[4], bg[4];                                                     \
      _Pragma("unroll") for (int i = 0; i < 4; ++i) {                          \
        int row = wr * 64 + i * 16 + l15;                                      \
        af[i] = *(const bf16x8*)&As[row * 64 + ((rb ^ (row & 7)) << 3)];       \
      }                                                                        \
      _Pragma("unroll") for (int j = 0; j < 4; ++j) {                          \
        int col = wc * 64 + j * 16 + l15;                                      \
        bg[j] = *(const bf16x8*)&Bs[col * 64 + ((rb ^ (col & 7)) << 3)];       \
      }                                                                        \
      _Pragma("unroll") for (int i = 0; i < 4; ++i)                            \
        _Pragma("unroll") for (int j = 0; j < 4; ++j)                          \
          acc[i][j] =                                                          \
              __builtin_amdgcn_mfma_f32_16x16x32_bf16(af[i], bg[j], acc[i][j], \
                                                      0, 0, 0);                \
    }                                                                          \
  }

  STAGE_G(0, 0);
  __syncthreads();
  for (int ks = 0; ks < NS - 1; ++ks) {
    STAGE_G(ks + 1, (ks + 1) & 1);
    COMPUTE_G(ks & 1);
    __syncthreads();
  }
  COMPUTE_G((NS - 1) & 1);

#undef STAGE_G
#undef COMPUTE_G

  if (EPI == 0) {
#pragma unroll
    for (int j = 0; j < 4; ++j) {
      int col = bx * 128 + wc * 64 + j * 16 + l15;
      float bj = bias ? bias[col] : 0.f;
#pragma unroll
      for (int i = 0; i < 4; ++i) {
        int row0 = by * 128 + wr * 64 + i * 16 + g * 4;
#pragma unroll
        for (int r = 0; r < 4; ++r)
          C[(size_t)(row0 + r) * N + col] = acc[i][j][r] + bj;
      }
    }
  } else if (EPI == 1) {
    __syncthreads();
#pragma unroll
    for (int j = 0; j < 4; ++j) {
      int cl = wc * 64 + j * 16 + l15;
      float bj = bias[bx * 128 + cl];
#pragma unroll
      for (int i = 0; i < 4; ++i) {
        int rl0 = wr * 64 + i * 16 + g * 4;
#pragma unroll
        for (int r = 0; r < 4; ++r) {
          float v = (acc[i][j][r] + bj) * 0.125f;
          ushort h = f2bf(v), lo = f2bf(v - bf2f(h));
          lds[(rl0 + r) * 128 + cl] = h;
          lds[16384 + (rl0 + r) * 128 + cl] = lo;
        }
      }
    }
    __syncthreads();
#pragma unroll
    for (int it = 0; it < 8; ++it) {
      int c = tid + it * 256;
      int r = c >> 4, ck = c & 15;
      int grow = by * 128 + r;
      size_t base = ((size_t)grow * 8 + bx * 2 + (ck >> 3)) * 128 + (ck & 7) * 8;
      *(uint4*)(Qs + base) = *(const uint4*)&lds[r * 128 + ck * 8];
      *(uint4*)(Qs + base + 64) = *(const uint4*)&lds[16384 + r * 128 + ck * 8];
    }
  } else {
    // EPI=2: kv epilogue — scatter split-bf16 directly into Kq / Vt layouts.
#pragma unroll
    for (int j = 0; j < 4; ++j) {
      int col = bx * 128 + wc * 64 + j * 16 + l15;
      float bj = bias[col];
      bool isK = col < 512;
      int cp = isK ? col : col - 512;
      int hh = cp >> 6, d = cp & 63;
#pragma unroll
      for (int i = 0; i < 4; ++i) {
        int row0 = by * 128 + wr * 64 + i * 16 + g * 4;
#pragma unroll
        for (int r = 0; r < 4; ++r) {
          int row = row0 + r;
          int b = row >> 8, kk = row & 255;
          float v = acc[i][j][r] + bj;
          ushort h = f2bf(v), lo = f2bf(v - bf2f(h));
          if (isK) {
            size_t base = ((size_t)((b * 8 + hh) * 256) + kk) * 128 + d;
            Kq[base] = h; Kq[base + 64] = lo;
          } else {
            size_t base = ((size_t)((b * 8 + hh) * 64) + d) * 512 + kk;
            Vt[base] = h; Vt[base + 256] = lo;
          }
        }
      }
    }
  }
}

// ---------------- conv body: one tap per block, pure bf16, 8 K-steps ----------------
// xq hi-only [16384][512]; Wsr_ hi-only [16 taps][512 co][512 ci].
__device__ __forceinline__ void conv_body(
    const ushort* __restrict__ xq, const ushort* __restrict__ Wsr_,
    float* __restrict__ part, int bx, int by, int z, ushort* lds) {
  int kh = z >> 2, kw = z & 3;
  int tid = threadIdx.x;
  int lane = tid & 63, w = tid >> 6;
  int wr = w >> 1, wc = w & 1;
  int l15 = lane & 15, g = lane >> 4;
  int srow = lane >> 3;
  int scol = (lane & 7) ^ srow;

  const ushort* aBase[4];
#pragma unroll
  for (int t = 0; t < 4; ++t) {
    int gm = by * 128 + w * 32 + t * 8 + srow;
    int xr = (gm >> 8) * 4096 + ((((gm >> 4) & 15) << 2) + kh) * 64 +
             ((gm & 15) << 2) + kw;
    aBase[t] = xq + (size_t)xr * 512 + scol * 8;
  }
  const ushort* bBase =
      Wsr_ + ((size_t)(z * 512 + bx * 128 + w * 32 + srow)) * 512 + scol * 8;

  f32x4 acc[4][4];
#pragma unroll
  for (int i = 0; i < 4; ++i)
#pragma unroll
    for (int j = 0; j < 4; ++j) acc[i][j] = (f32x4){0.f, 0.f, 0.f, 0.f};

#define STAGE_C(ks, buf)                                              \
  {                                                                   \
    int kk = (ks) * 64;                                               \
    ushort* aD = lds + (buf) * 16384 + w * 2048;                      \
    ushort* bD = lds + (buf) * 16384 + 8192 + w * 2048;               \
    _Pragma("unroll") for (int t = 0; t < 4; ++t) {                   \
      gload16(aBase[t] + kk, aD + t * 512);                           \
      gload16(bBase + (size_t)t * 4096 + kk, bD + t * 512);           \
    }                                                                 \
  }

#define COMPUTE_C(buf)                                                         \
  {                                                                            \
    const ushort* As = lds + (buf) * 16384;                                    \
    const ushort* Bs = As + 8192;                                              \
    _Pragma("unroll") for (int kk2 = 0; kk2 < 2; ++kk2) {                      \
      int rb = kk2 * 4 + g;                                                    \
      bf16x8 af[4], bg[4];                                                     \
      _Pragma("unroll") for (int i = 0; i < 4; ++i) {                          \
        int row = wr * 64 + i * 16 + l15;                                      \
        af[i] = *(const bf16x8*)&As[row * 64 + ((rb ^ (row & 7)) << 3)];       \
      }                                                                        \
      _Pragma("unroll") for (int j = 0; j < 4; ++j) {                          \
        int col = wc * 64 + j * 16 + l15;                                      \
        bg[j] = *(const bf16x8*)&Bs[col * 64 + ((rb ^ (col & 7)) << 3)];       \
      }                                                                        \
      _Pragma("unroll") for (int i = 0; i < 4; ++i)                            \
        _Pragma("unroll") for (int j = 0; j < 4; ++j)                          \
          acc[i][j] =                                                          \
              __builtin_amdgcn_mfma_f32_16x16x32_bf16(af[i], bg[j], acc[i][j], \
                                                      0, 0, 0);                \
    }                                                                          \
  }

  STAGE_C(0, 0);
  __syncthreads();
  for (int ks = 0; ks < 7; ++ks) {
    STAGE_C(ks + 1, (ks + 1) & 1);
    COMPUTE_C(ks & 1);
    __syncthreads();
  }
  COMPUTE_C(1);

#undef STAGE_C
#undef COMPUTE_C

  float* Cp = part + (size_t)z * 524288;
#pragma unroll
  for (int j = 0; j < 4; ++j) {
    int col = bx * 128 + wc * 64 + j * 16 + l15;
#pragma unroll
    for (int i = 0; i < 4; ++i) {
      int row0 = by * 128 + wr * 64 + i * 16 + g * 4;
#pragma unroll
      for (int r = 0; r < 4; ++r)
        Cp[(size_t)(row0 + r) * 512 + col] = acc[i][j][r];
    }
  }
}

// conv only: 512 blocks, uniform 8 steps
__global__ __launch_bounds__(256) void conv_kernel(
    const ushort* __restrict__ xq, const ushort* __restrict__ Wsr_,
    float* __restrict__ part) {
  __shared__ __align__(16) ushort lds[32768];
  int bid = xcd_swz(blockIdx.x, 512);
  conv_body(xq, Wsr_, part, bid & 3, (bid >> 2) & 7, bid >> 5, lds);
}

// q-proj (512 x 8-step) + kv-proj (64 x 24-step) in one launch.
// xcd = n&7 (hardware round-robin), slot = n>>3; slot<8 -> kvproj FIRST.
// Per XCD: 8 long (24-step) + 64 short (8-step) over 32 CUs -> makespan ~24.
__global__ __launch_bounds__(256) void qkv_kernel(
    const ushort* __restrict__ xq, const ushort* __restrict__ Wq_,
    const float* __restrict__ bq, ushort* __restrict__ Qs,
    const ushort* __restrict__ xkv_, const ushort* __restrict__ Wkv_,
    const float* __restrict__ bkv, ushort* __restrict__ Kq,
    ushort* __restrict__ Vt) {
  __shared__ __align__(16) ushort lds[32768];
  int n = blockIdx.x;  // 576
  int xcd = n & 7, slot = n >> 3;
  if (slot < 8) {
    int id = xcd * 8 + slot;  // 0..63
    gemm_body<2, 3>(xkv_, Wkv_, bkv, nullptr, nullptr, Kq, Vt, 1024,
                    id & 7, id >> 3, lds);
  } else {
    int id = xcd * 64 + (slot - 8);  // 0..511
    gemm_body<1, 1>(xq, Wq_, bq, nullptr, Qs, nullptr, nullptr, 512,
                    id & 3, id >> 2, lds);
  }
}

// out-proj (pure bf16: attno-hi x Wp-hi)
__global__ __launch_bounds__(256) void gemm_out_kernel(
    const ushort* __restrict__ A, const ushort* __restrict__ Bw,
    const float* __restrict__ bias, float* __restrict__ C) {
  __shared__ __align__(16) ushort lds[32768];
  int bid = xcd_swz(blockIdx.x, 512);
  gemm_body<0, 1>(A, Bw, bias, C, nullptr, nullptr, nullptr, 512,
                  bid & 3, bid >> 2, lds);
}

// ---------------- partial-sum(16) + bias + LayerNorm -> split-bf16 ----------------
__global__ __launch_bounds__(256) void ln_kernel(
    const float* __restrict__ part, const float* __restrict__ bsr,
    const float* __restrict__ gamma, const float* __restrict__ beta,
    ushort* __restrict__ xkv_) {
  int row = blockIdx.x;
  int t = threadIdx.x;
  float v0 = bsr[t], v1 = bsr[t + 256];
  for (int p = 0; p < 16; ++p) {
    v0 += part[(size_t)p * 524288 + (size_t)row * 512 + t];
    v1 += part[(size_t)p * 524288 + (size_t)row * 512 + t + 256];
  }
  float s = v0 + v1, sq = v0 * v0 + v1 * v1;
#pragma unroll
  for (int o = 1; o < 64; o <<= 1) {
    s += __shfl_xor(s, o);
    sq += __shfl_xor(sq, o);
  }
  __shared__ float red[8];
  int wv = t >> 6;
  if ((t & 63) == 0) { red[wv] = s; red[4 + wv] = sq; }
  __syncthreads();
  s = red[0] + red[1] + red[2] + red[3];
  sq = red[4] + red[5] + red[6] + red[7];
  float mu = s * (1.0f / 512.0f);
  float var = sq * (1.0f / 512.0f) - mu * mu;
  float rs = rsqrtf(var + 1e-5f);
  float y0 = (v0 - mu) * rs * gamma[t] + beta[t];
  float y1 = (v1 - mu) * rs * gamma[t + 256] + beta[t + 256];
  ushort h0 = f2bf(y0), h1 = f2bf(y1);
  xkv_[(size_t)row * 1024 + t] = h0;
  xkv_[(size_t)row * 1024 + t + 256] = h1;
  xkv_[(size_t)row * 1024 + 512 + t] = f2bf(y0 - bf2f(h0));
  xkv_[(size_t)row * 1024 + 512 + t + 256] = f2bf(y1 - bf2f(h1));
}

// ---------------- MFMA flash attention: 128 q/block, QK 2-term, dbuf DMA ----------------
// attno output: hi-only [16384][512].
__global__ __launch_bounds__(256, 2) void attn_kernel(
    const ushort* __restrict__ Qs, const ushort* __restrict__ Kq,
    const ushort* __restrict__ Vt, ushort* __restrict__ attno) {
  __shared__ __align__(16) char arena[65536];
  ushort* KsL = (ushort*)arena;            // [2][64 kk][64 hi], swizzled
  ushort* VtL = (ushort*)(arena + 16384);  // [2][64 d][128 hi|lo kk]
  ushort* PL = (ushort*)(arena + 49152);   // [128 q][64 kk] bf16, swizzled
  float* ob = (float*)arena;               // epilogue alias

  int tid = threadIdx.x;
  int qb = blockIdx.x, h = blockIdx.y, b = blockIdx.z;
  int n0 = qb * 128, bh = b * 8 + h;
  int lane = tid & 63, w = tid >> 6;
  int q15 = lane & 15, g = lane >> 4;

  const ushort* kbase = Kq + (size_t)bh * 256 * 128;
  const ushort* vbase = Vt + (size_t)bh * 64 * 512;

  bf16x8 qf[2][2][2];
#pragma unroll
  for (int set = 0; set < 2; ++set) {
    const ushort* qptr =
        Qs + ((size_t)(b * 4096 + n0 + set * 64 + w * 16 + q15) * 8 + h) * 128;
#pragma unroll
    for (int s = 0; s < 2; ++s)
#pragma unroll
      for (int kb = 0; kb < 2; ++kb)
        qf[set][s][kb] = *(const bf16x8*)(qptr + s * 64 + kb * 32 + g * 8);
  }

  f32x4 accO[2][4];
#pragma unroll
  for (int set = 0; set < 2; ++set)
#pragma unroll
    for (int t = 0; t < 4; ++t) accO[set][t] = (f32x4){0.f, 0.f, 0.f, 0.f};
  float m[2] = {-1e30f, -1e30f}, l[2] = {0.f, 0.f};

#define STAGE_A(cc, buf)                                                     \
  {                                                                          \
    _Pragma("unroll") for (int i = 0; i < 2; ++i) {                          \
      int rb_ = w * 16 + i * 8;                                              \
      int r_ = rb_ + (lane >> 3);                                            \
      int sb_ = (lane & 7) ^ (r_ & 7);                                       \
      gload16(kbase + (size_t)((cc) * 64 + r_) * 128 + (sb_ << 3),           \
              KsL + (buf) * 4096 + rb_ * 64);                                \
    }                                                                        \
    _Pragma("unroll") for (int i = 0; i < 4; ++i) {                          \
      int rb_ = w * 16 + i * 4;                                              \
      int r_ = rb_ + (lane >> 4);                                            \
      int sb_ = (lane & 15) ^ (r_ & 7);                                      \
      gload16(vbase + (size_t)r_ * 512 + ((sb_ >> 3) << 8) + (cc) * 64 +     \
                  ((sb_ & 7) << 3),                                          \
              VtL + (buf) * 8192 + rb_ * 128);                               \
    }                                                                        \
  }

  STAGE_A(0, 0);
  __syncthreads();

  for (int c = 0; c < 4; ++c) {
    int buf = c & 1;
    if (c < 3) STAGE_A(c + 1, buf ^ 1);
    const ushort* Ks = KsL + buf * 4096;
    const ushort* Vs = VtL + buf * 8192;

    // S^T = Khi*Qhi + Khi*Qlo (2-term)
    f32x4 accS[2][4];
#pragma unroll
    for (int set = 0; set < 2; ++set)
#pragma unroll
      for (int t = 0; t < 4; ++t) accS[set][t] = (f32x4){0.f, 0.f, 0.f, 0.f};
#pragma unroll
    for (int kb = 0; kb < 2; ++kb) {
      bf16x8 ak[4];
#pragma unroll
      for (int t = 0; t < 4; ++t) {
        int kkr = t * 16 + q15;
        ak[t] = *(const bf16x8*)&Ks[kkr * 64 + (((kb * 4 + g) ^ (kkr & 7)) << 3)];
      }
#pragma unroll
      for (int set = 0; set < 2; ++set) {
#pragma unroll
        for (int t = 0; t < 4; ++t)
          accS[set][t] = __builtin_amdgcn_mfma_f32_16x16x32_bf16(
              ak[t], qf[set][0][kb], accS[set][t], 0, 0, 0);
#pragma unroll
        for (int t = 0; t < 4; ++t)
          accS[set][t] = __builtin_amdgcn_mfma_f32_16x16x32_bf16(
              ak[t], qf[set][1][kb], accS[set][t], 0, 0, 0);
      }
    }

#pragma unroll
    for (int set = 0; set < 2; ++set) {
      int qrowL = set * 64 + w * 16 + q15;
      float mx = -1e30f;
#pragma unroll
      for (int t = 0; t < 4; ++t)
#pragma unroll
        for (int r = 0; r < 4; ++r) mx = fmaxf(mx, accS[set][t][r]);
      mx = fmaxf(mx, __shfl_xor(mx, 16));
      mx = fmaxf(mx, __shfl_xor(mx, 32));
      float mn = fmaxf(m[set], mx);
      float fac = __expf(m[set] - mn);
      m[set] = mn;
      float sum = 0.f;
      ushort ph[4][4];
#pragma unroll
      for (int t = 0; t < 4; ++t)
#pragma unroll
        for (int r = 0; r < 4; ++r) {
          float p = __expf(accS[set][t][r] - mn);
          ushort hp = f2bf(p);
          ph[t][r] = hp;
          sum += bf2f(hp);
        }
      sum += __shfl_xor(sum, 16);
      sum += __shfl_xor(sum, 32);
      l[set] = l[set] * fac + sum;
#pragma unroll
      for (int t = 0; t < 4; ++t) {
        accO[set][t][0] *= fac; accO[set][t][1] *= fac;
        accO[set][t][2] *= fac; accO[set][t][3] *= fac;
      }
#pragma unroll
      for (int t = 0; t < 4; ++t)
#pragma unroll
        for (int rp = 0; rp < 4; rp += 2) {
          uint u = ph[t][rp] | ((uint)ph[t][rp + 1] << 16);
          int kkl = t * 16 + g * 4 + rp;
          int blk = kkl >> 3, off = kkl & 7;
          *(uint*)((char*)PL + qrowL * 128 + ((blk ^ (q15 & 7)) << 4) + off * 2) = u;
        }
    }
    __syncthreads();

    bf16x8 pf[2][2];
#pragma unroll
    for (int set = 0; set < 2; ++set) {
      int qrowL = set * 64 + w * 16 + q15;
#pragma unroll
      for (int kb = 0; kb < 2; ++kb)
        pf[set][kb] = *(const bf16x8*)((char*)PL + qrowL * 128 +
                                       (((kb * 4 + g) ^ (q15 & 7)) << 4));
    }
#pragma unroll
    for (int s = 0; s < 2; ++s)
#pragma unroll
      for (int kb = 0; kb < 2; ++kb)
#pragma unroll
        for (int t = 0; t < 4; ++t) {
          int d = t * 16 + q15;
          bf16x8 vf =
              *(const bf16x8*)&Vs[d * 128 + (((s * 8 + kb * 4 + g) ^ (d & 7)) << 3)];
          accO[0][t] = __builtin_amdgcn_mfma_f32_16x16x32_bf16(vf, pf[0][kb],
                                                               accO[0][t], 0, 0, 0);
          accO[1][t] = __builtin_amdgcn_mfma_f32_16x16x32_bf16(vf, pf[1][kb],
                                                               accO[1][t], 0, 0, 0);
        }
    __syncthreads();
  }
#undef STAGE_A

#pragma unroll
  for (int set = 0; set < 2; ++set) {
    if (set) __syncthreads();
    float inv = 1.0f / l[set];
#pragma unroll
    for (int t = 0; t < 4; ++t)
#pragma unroll
      for (int r = 0; r < 4; ++r)
        ob[(t * 16 + g * 4 + r) * 68 + w * 16 + q15] = accO[set][t][r] * inv;
    __syncthreads();
#pragma unroll
    for (int i = 0; i < 2; ++i) {
      int idx = tid + i * 256;
      int qq = idx >> 3, d8 = (idx & 7) << 3;
      ushort hh[8];
#pragma unroll
      for (int jj = 0; jj < 8; ++jj) hh[jj] = f2bf(ob[(d8 + jj) * 68 + qq]);
      uint4 hp;
      hp.x = hh[0] | ((uint)hh[1] << 16); hp.y = hh[2] | ((uint)hh[3] << 16);
      hp.z = hh[4] | ((uint)hh[5] << 16); hp.w = hh[6] | ((uint)hh[7] << 16);
      size_t rowb = (size_t)(b * 4096 + n0 + set * 64 + qq) * 512 + h * 64 + d8;
      *(uint4*)(attno + rowb) = hp;
    }
  }
}

// ---------------- launch ----------------
extern "C" void kernel_launch(void* const* d_in, const int* in_sizes, int n_in,
                              void* d_out, int out_size, void* d_ws, size_t ws_size,
                              hipStream_t stream) {
  const float* x     = (const float*)d_in[0];
  const float* Wq    = (const float*)d_in[1];
  const float* bq    = (const float*)d_in[2];
  const float* Wk    = (const float*)d_in[3];
  const float* bk    = (const float*)d_in[4];
  const float* Wv    = (const float*)d_in[5];
  const float* bv    = (const float*)d_in[6];
  const float* Wp    = (const float*)d_in[7];
  const float* bp    = (const float*)d_in[8];
  const float* Wsr   = (const float*)d_in[9];
  const float* bsr   = (const float*)d_in[10];
  const float* gamma = (const float*)d_in[11];
  const float* beta  = (const float*)d_in[12];

  float* ws = (float*)d_ws;
  // Layout (68.2MB):
  //   xq hi [16384][512] us = 4,194,304 fl  (dies after qkv; attno_ aliases)
  //   conv_part [16][1024][512] f32 = 8,388,608 fl at +4,194,304
  //   Qsplit 16,777,216 us aliases conv_part (written after ln)
  //   Wsr_ 4,194,304 us = 2,097,152 fl at +12,582,912
  //   rest at +14,680,064
  ushort* xq     = (ushort*)ws;
  ushort* attno_ = (ushort*)ws;
  float*  conv_part = ws + 4194304;
  ushort* Qsplit = (ushort*)(ws + 4194304);
  ushort* Wsr_ = (ushort*)(ws + 12582912);
  float*  rest = ws + 14680064;
  ushort* Wq_  = (ushort*)rest;                 // 262,144 us = 131,072 fl
  ushort* Wp_  = (ushort*)(rest + 131072);      // 262,144 us
  ushort* Wkv_ = (ushort*)(rest + 262144);      // 1,048,576 us = 524,288 fl
  ushort* xkv_ = (ushort*)(rest + 786432);      // 1,048,576 us
  ushort* Kq   = (ushort*)(rest + 1310720);     // 1,048,576 us
  ushort* Vt   = (ushort*)(rest + 1835008);     // 1,048,576 us
  float*  bkv  = rest + 2359296;                // 1,024 fl
  float* outp = (float*)d_out;

  prep_kernel<<<8705, 256, 0, stream>>>(x, Wq, Wp, Wk, Wv, Wsr, bk, bv,
                                        xq, Wq_, Wp_, Wkv_, Wsr_, bkv);
  conv_kernel<<<512, 256, 0, stream>>>(xq, Wsr_, conv_part);
  ln_kernel<<<1024, 256, 0, stream>>>(conv_part, bsr, gamma, beta, xkv_);
  qkv_kernel<<<576, 256, 0, stream>>>(xq, Wq_, bq, Qsplit,
                                      xkv_, Wkv_, bkv, Kq, Vt);
  attn_kernel<<<dim3(32, 8, 4), 256, 0, stream>>>(Qsplit, Kq, Vt, attno_);
  gemm_out_kernel<<<512, 256, 0, stream>>>(attno_, Wp_, bp, outp);
}

// Round 17
// 99.625 us; speedup vs baseline: 1.7476x; 1.2052x over previous
//
#include <hip/hip_runtime.h>

// B=4, H=W=64, N=4096, C=512, HEAD=8, dh=64, SR=4, Nk=256
// Full bf16 pipeline (empirically validated: absmax moved 2.441e-4 -> 2.518e-4
// across three ~2e-3-scale term drops; all remaining drops contribute <1e-4
// in quadrature; threshold 1.26e-3):
//   all GEMMs pure bf16 (hi*hi, K=512, 8 K-steps), fp32 MFMA accumulate;
//   attn QK 1-term, PV 1-term; Q/K/V/attno stored hi-only.
// LESSON r13: mixed-length blocks must be spread long-first per XCD (now moot:
// every GEMM block is uniform 8-step).

typedef __bf16 bf16x8 __attribute__((ext_vector_type(8)));
typedef float f32x4 __attribute__((ext_vector_type(4)));

__device__ __forceinline__ ushort f2bf(float v) {
  uint u = __float_as_uint(v);
  return (ushort)((u + 0x7FFFu + ((u >> 16) & 1u)) >> 16);
}
__device__ __forceinline__ float bf2f(ushort h) {
  return __uint_as_float((uint)h << 16);
}
__device__ __forceinline__ void gload16(const void* g, void* l) {
  __builtin_amdgcn_global_load_lds(
      (const __attribute__((address_space(1))) void*)g,
      (__attribute__((address_space(3))) void*)l, 16, 0, 0);
}
// bijective XCD swizzle for nwg % 8 == 0
__device__ __forceinline__ int xcd_swz(int bid, int nwg) {
  int cpx = nwg >> 3;
  return (bid & 7) * cpx + (bid >> 3);
}

// ---------------- fused prep: everything -> hi-only bf16 ----------------
// x -> xq [16384][512]; Wq/Wp -> [512][512]; Wk|Wv -> Wkv_ [1024][512];
// Wsr -> transposed [16][512 co][512 ci]; bkv concat.
__global__ __launch_bounds__(256) void prep_kernel(
    const float* __restrict__ x, const float* __restrict__ Wq,
    const float* __restrict__ Wp, const float* __restrict__ Wk,
    const float* __restrict__ Wv, const float* __restrict__ Wsr,
    const float* __restrict__ bk, const float* __restrict__ bv,
    ushort* __restrict__ xq, ushort* __restrict__ Wq_,
    ushort* __restrict__ Wp_, ushort* __restrict__ Wkv_,
    ushort* __restrict__ Wsr_, float* __restrict__ bkv) {
  __shared__ float t[32][33];
  int bid = blockIdx.x, tid = threadIdx.x;
  if (bid < 4096 + 512) {
    const float* src;
    ushort* dst;
    int gid;
    if (bid < 4096) {
      src = x; dst = xq; gid = bid * 256 + tid;
    } else {
      int z = (bid - 4096) >> 7;
      src = (z == 0) ? Wq : (z == 1) ? Wp : (z == 2) ? Wk : Wv;
      dst = (z == 0) ? Wq_ : (z == 1) ? Wp_ : (z == 2) ? Wkv_ : (Wkv_ + 512 * 512);
      gid = ((bid - 4096) & 127) * 256 + tid;
    }
    int row = gid >> 6, c8 = (gid & 63) << 3;
    float4 a = *(const float4*)(src + (size_t)row * 512 + c8);
    float4 b = *(const float4*)(src + (size_t)row * 512 + c8 + 4);
    ushort h[8];
    float vv[8] = {a.x, a.y, a.z, a.w, b.x, b.y, b.z, b.w};
#pragma unroll
    for (int e = 0; e < 8; ++e) h[e] = f2bf(vv[e]);
    uint4 hp;
    hp.x = h[0] | ((uint)h[1] << 16); hp.y = h[2] | ((uint)h[3] << 16);
    hp.z = h[4] | ((uint)h[5] << 16); hp.w = h[6] | ((uint)h[7] << 16);
    *(uint4*)(dst + (size_t)row * 512 + c8) = hp;
  } else if (bid < 4096 + 512 + 4096) {
    int tb = bid - 4608;
    int z = tb >> 8, rem = tb & 255;
    int ci0 = (rem >> 4) << 5, co0 = (rem & 15) << 5;
    int tx = tid & 31, ty = tid >> 5;
#pragma unroll
    for (int i = 0; i < 32; i += 8)
      t[ty + i][tx] = Wsr[((size_t)z * 512 + ci0 + ty + i) * 512 + co0 + tx];
    __syncthreads();
#pragma unroll
    for (int i = 0; i < 32; i += 8) {
      float v = t[tx][ty + i];
      int co = co0 + ty + i, ci = ci0 + tx;
      Wsr_[((size_t)z * 512 + co) * 512 + ci] = f2bf(v);
    }
  } else {
    bkv[tid] = bk[tid]; bkv[tid + 256] = bk[tid + 256];
    bkv[tid + 512] = bv[tid]; bkv[tid + 768] = bv[tid + 256];
  }
}

// ---------------- MFMA GEMM body: pure bf16, 8 K-steps, dbuf 2-phase ----------------
// EPI=0: C fp32 + bias. EPI=1: Q hi-only per-head layout (LDS-coalesced).
// EPI=2: Kq/Vt hi-only scatter.
template <int EPI>
__device__ __forceinline__ void gemm_body(
    const ushort* __restrict__ A, const ushort* __restrict__ Bw,
    const float* __restrict__ bias, float* __restrict__ C,
    ushort* __restrict__ Qs, ushort* __restrict__ Kq, ushort* __restrict__ Vt,
    int N, int bx, int by, ushort* lds) {
  int tid = threadIdx.x;
  int lane = tid & 63, w = tid >> 6;
  int wr = w >> 1, wc = w & 1;
  int l15 = lane & 15, g = lane >> 4;
  int srow = lane >> 3;
  int scol = (lane & 7) ^ srow;

  const ushort* aBase = A + (size_t)(by * 128 + w * 32 + srow) * 512 + scol * 8;
  const ushort* bBase = Bw + (size_t)(bx * 128 + w * 32 + srow) * 512 + scol * 8;

  f32x4 acc[4][4];
#pragma unroll
  for (int i = 0; i < 4; ++i)
#pragma unroll
    for (int j = 0; j < 4; ++j) acc[i][j] = (f32x4){0.f, 0.f, 0.f, 0.f};

#define STAGE_G(ks, buf)                                              \
  {                                                                   \
    int kk = (ks) * 64;                                               \
    ushort* aD = lds + (buf) * 16384 + w * 2048;                      \
    ushort* bD = lds + (buf) * 16384 + 8192 + w * 2048;               \
    _Pragma("unroll") for (int t = 0; t < 4; ++t) {                   \
      gload16(aBase + (size_t)t * 4096 + kk, aD + t * 512);           \
      gload16(bBase + (size_t)t * 4096 + kk, bD + t * 512);           \
    }                                                                 \
  }

#define COMPUTE_G(buf)                                                         \
  {                                                                            \
    const ushort* As = lds + (buf) * 16384;                                    \
    const ushort* Bs = As + 8192;                                              \
    _Pragma("unroll") for (int kk2 = 0; kk2 < 2; ++kk2) {                      \
      int rb = kk2 * 4 + g;                                                    \
      bf16x8 af[4], bg[4];                                                     \
      _Pragma("unroll") for (int i = 0; i < 4; ++i) {                          \
        int row = wr * 64 + i * 16 + l15;                                      \
        af[i] = *(const bf16x8*)&As[row * 64 + ((rb ^ (row & 7)) << 3)];       \
      }                                                                        \
      _Pragma("unroll") for (int j = 0; j < 4; ++j) {                          \
        int col = wc * 64 + j * 16 + l15;                                      \
        bg[j] = *(const bf16x8*)&Bs[col * 64 + ((rb ^ (col & 7)) << 3)];       \
      }                                                                        \
      _Pragma("unroll") for (int i = 0; i < 4; ++i)                            \
        _Pragma("unroll") for (int j = 0; j < 4; ++j)                          \
          acc[i][j] =                                                          \
              __builtin_amdgcn_mfma_f32_16x16x32_bf16(af[i], bg[j], acc[i][j], \
                                                      0, 0, 0);                \
    }                                                                          \
  }

  STAGE_G(0, 0);
  __syncthreads();
  for (int ks = 0; ks < 7; ++ks) {
    STAGE_G(ks + 1, (ks + 1) & 1);
    COMPUTE_G(ks & 1);
    __syncthreads();
  }
  COMPUTE_G(1);

#undef STAGE_G
#undef COMPUTE_G

  if (EPI == 0) {
#pragma unroll
    for (int j = 0; j < 4; ++j) {
      int col = bx * 128 + wc * 64 + j * 16 + l15;
      float bj = bias ? bias[col] : 0.f;
#pragma unroll
      for (int i = 0; i < 4; ++i) {
        int row0 = by * 128 + wr * 64 + i * 16 + g * 4;
#pragma unroll
        for (int r = 0; r < 4; ++r)
          C[(size_t)(row0 + r) * N + col] = acc[i][j][r] + bj;
      }
    }
  } else if (EPI == 1) {
    // Q hi-only [row][8 head][64], coalesced via LDS round-trip
    __syncthreads();
#pragma unroll
    for (int j = 0; j < 4; ++j) {
      int cl = wc * 64 + j * 16 + l15;
      float bj = bias[bx * 128 + cl];
#pragma unroll
      for (int i = 0; i < 4; ++i) {
        int rl0 = wr * 64 + i * 16 + g * 4;
#pragma unroll
        for (int r = 0; r < 4; ++r)
          lds[(rl0 + r) * 128 + cl] = f2bf((acc[i][j][r] + bj) * 0.125f);
      }
    }
    __syncthreads();
#pragma unroll
    for (int it = 0; it < 8; ++it) {
      int c = tid + it * 256;
      int r = c >> 4, ck = c & 15;
      int grow = by * 128 + r;
      size_t base = ((size_t)grow * 8 + bx * 2 + (ck >> 3)) * 64 + (ck & 7) * 8;
      *(uint4*)(Qs + base) = *(const uint4*)&lds[r * 128 + ck * 8];
    }
  } else {
    // EPI=2: Kq [bh][256 kk][64 d] hi; Vt [bh][64 d][256 kk] hi.
#pragma unroll
    for (int j = 0; j < 4; ++j) {
      int col = bx * 128 + wc * 64 + j * 16 + l15;
      float bj = bias[col];
      bool isK = col < 512;
      int cp = isK ? col : col - 512;
      int hh = cp >> 6, d = cp & 63;
#pragma unroll
      for (int i = 0; i < 4; ++i) {
        int row0 = by * 128 + wr * 64 + i * 16 + g * 4;
#pragma unroll
        for (int r = 0; r < 4; ++r) {
          int row = row0 + r;
          int b = row >> 8, kk = row & 255;
          ushort h = f2bf(acc[i][j][r] + bj);
          if (isK)
            Kq[((size_t)((b * 8 + hh) * 256) + kk) * 64 + d] = h;
          else
            Vt[((size_t)((b * 8 + hh) * 64) + d) * 256 + kk] = h;
        }
      }
    }
  }
}

// ---------------- conv body: one tap per block, pure bf16, 8 K-steps ----------------
__device__ __forceinline__ void conv_body(
    const ushort* __restrict__ xq, const ushort* __restrict__ Wsr_,
    float* __restrict__ part, int bx, int by, int z, ushort* lds) {
  int kh = z >> 2, kw = z & 3;
  int tid = threadIdx.x;
  int lane = tid & 63, w = tid >> 6;
  int wr = w >> 1, wc = w & 1;
  int l15 = lane & 15, g = lane >> 4;
  int srow = lane >> 3;
  int scol = (lane & 7) ^ srow;

  const ushort* aBase[4];
#pragma unroll
  for (int t = 0; t < 4; ++t) {
    int gm = by * 128 + w * 32 + t * 8 + srow;
    int xr = (gm >> 8) * 4096 + ((((gm >> 4) & 15) << 2) + kh) * 64 +
             ((gm & 15) << 2) + kw;
    aBase[t] = xq + (size_t)xr * 512 + scol * 8;
  }
  const ushort* bBase =
      Wsr_ + ((size_t)(z * 512 + bx * 128 + w * 32 + srow)) * 512 + scol * 8;

  f32x4 acc[4][4];
#pragma unroll
  for (int i = 0; i < 4; ++i)
#pragma unroll
    for (int j = 0; j < 4; ++j) acc[i][j] = (f32x4){0.f, 0.f, 0.f, 0.f};

#define STAGE_C(ks, buf)                                              \
  {                                                                   \
    int kk = (ks) * 64;                                               \
    ushort* aD = lds + (buf) * 16384 + w * 2048;                      \
    ushort* bD = lds + (buf) * 16384 + 8192 + w * 2048;               \
    _Pragma("unroll") for (int t = 0; t < 4; ++t) {                   \
      gload16(aBase[t] + kk, aD + t * 512);                           \
      gload16(bBase + (size_t)t * 4096 + kk, bD + t * 512);           \
    }                                                                 \
  }

#define COMPUTE_C(buf)                                                         \
  {                                                                            \
    const ushort* As = lds + (buf) * 16384;                                    \
    const ushort* Bs = As + 8192;                                              \
    _Pragma("unroll") for (int kk2 = 0; kk2 < 2; ++kk2) {                      \
      int rb = kk2 * 4 + g;                                                    \
      bf16x8 af[4], bg[4];                                                     \
      _Pragma("unroll") for (int i = 0; i < 4; ++i) {                          \
        int row = wr * 64 + i * 16 + l15;                                      \
        af[i] = *(const bf16x8*)&As[row * 64 + ((rb ^ (row & 7)) << 3)];       \
      }                                                                        \
      _Pragma("unroll") for (int j = 0; j < 4; ++j) {                          \
        int col = wc * 64 + j * 16 + l15;                                      \
        bg[j] = *(const bf16x8*)&Bs[col * 64 + ((rb ^ (col & 7)) << 3)];       \
      }                                                                        \
      _Pragma("unroll") for (int i = 0; i < 4; ++i)                            \
        _Pragma("unroll") for (int j = 0; j < 4; ++j)                          \
          acc[i][j] =                                                          \
              __builtin_amdgcn_mfma_f32_16x16x32_bf16(af[i], bg[j], acc[i][j], \
                                                      0, 0, 0);                \
    }                                                                          \
  }

  STAGE_C(0, 0);
  __syncthreads();
  for (int ks = 0; ks < 7; ++ks) {
    STAGE_C(ks + 1, (ks + 1) & 1);
    COMPUTE_C(ks & 1);
    __syncthreads();
  }
  COMPUTE_C(1);

#undef STAGE_C
#undef COMPUTE_C

  float* Cp = part + (size_t)z * 524288;
#pragma unroll
  for (int j = 0; j < 4; ++j) {
    int col = bx * 128 + wc * 64 + j * 16 + l15;
#pragma unroll
    for (int i = 0; i < 4; ++i) {
      int row0 = by * 128 + wr * 64 + i * 16 + g * 4;
#pragma unroll
      for (int r = 0; r < 4; ++r)
        Cp[(size_t)(row0 + r) * 512 + col] = acc[i][j][r];
    }
  }
}

// conv: 512 blocks, uniform 8 steps
__global__ __launch_bounds__(256) void conv_kernel(
    const ushort* __restrict__ xq, const ushort* __restrict__ Wsr_,
    float* __restrict__ part) {
  __shared__ __align__(16) ushort lds[32768];
  int bid = xcd_swz(blockIdx.x, 512);
  conv_body(xq, Wsr_, part, bid & 3, (bid >> 2) & 7, bid >> 5, lds);
}

// q-proj (512) + kv-proj (64): 576 uniform 8-step blocks.
__global__ __launch_bounds__(256) void qkv_kernel(
    const ushort* __restrict__ xq, const ushort* __restrict__ Wq_,
    const float* __restrict__ bq, ushort* __restrict__ Qs,
    const ushort* __restrict__ xkv_, const ushort* __restrict__ Wkv_,
    const float* __restrict__ bkv, ushort* __restrict__ Kq,
    ushort* __restrict__ Vt) {
  __shared__ __align__(16) ushort lds[32768];
  int n = blockIdx.x;  // 576
  int xcd = n & 7, slot = n >> 3;
  if (slot < 8) {
    int id = xcd * 8 + slot;  // 0..63
    gemm_body<2>(xkv_, Wkv_, bkv, nullptr, nullptr, Kq, Vt, 1024,
                 id & 7, id >> 3, lds);
  } else {
    int id = xcd * 64 + (slot - 8);  // 0..511
    gemm_body<1>(xq, Wq_, bq, nullptr, Qs, nullptr, nullptr, 512,
                 id & 3, id >> 2, lds);
  }
}

// out-proj (pure bf16)
__global__ __launch_bounds__(256) void gemm_out_kernel(
    const ushort* __restrict__ A, const ushort* __restrict__ Bw,
    const float* __restrict__ bias, float* __restrict__ C) {
  __shared__ __align__(16) ushort lds[32768];
  int bid = xcd_swz(blockIdx.x, 512);
  gemm_body<0>(A, Bw, bias, C, nullptr, nullptr, nullptr, 512,
               bid & 3, bid >> 2, lds);
}

// ---------------- partial-sum(16) + bias + LayerNorm -> bf16 hi ----------------
__global__ __launch_bounds__(256) void ln_kernel(
    const float* __restrict__ part, const float* __restrict__ bsr,
    const float* __restrict__ gamma, const float* __restrict__ beta,
    ushort* __restrict__ xkv_) {
  int row = blockIdx.x;
  int t = threadIdx.x;
  float v0 = bsr[t], v1 = bsr[t + 256];
  for (int p = 0; p < 16; ++p) {
    v0 += part[(size_t)p * 524288 + (size_t)row * 512 + t];
    v1 += part[(size_t)p * 524288 + (size_t)row * 512 + t + 256];
  }
  float s = v0 + v1, sq = v0 * v0 + v1 * v1;
#pragma unroll
  for (int o = 1; o < 64; o <<= 1) {
    s += __shfl_xor(s, o);
    sq += __shfl_xor(sq, o);
  }
  __shared__ float red[8];
  int wv = t >> 6;
  if ((t & 63) == 0) { red[wv] = s; red[4 + wv] = sq; }
  __syncthreads();
  s = red[0] + red[1] + red[2] + red[3];
  sq = red[4] + red[5] + red[6] + red[7];
  float mu = s * (1.0f / 512.0f);
  float var = sq * (1.0f / 512.0f) - mu * mu;
  float rs = rsqrtf(var + 1e-5f);
  xkv_[(size_t)row * 512 + t] = f2bf((v0 - mu) * rs * gamma[t] + beta[t]);
  xkv_[(size_t)row * 512 + t + 256] =
      f2bf((v1 - mu) * rs * gamma[t + 256] + beta[t + 256]);
}

// ---------------- MFMA flash attention: 128 q/block, 1-term QK & PV ----------------
// Q/K/V hi-only; attno hi-only [16384][512].
__global__ __launch_bounds__(256, 2) void attn_kernel(
    const ushort* __restrict__ Qs, const ushort* __restrict__ Kq,
    const ushort* __restrict__ Vt, ushort* __restrict__ attno) {
  __shared__ __align__(16) char arena[49152];
  ushort* KsL = (ushort*)arena;            // [2][64 kk][64], swizzled
  ushort* VtL = (ushort*)(arena + 16384);  // [2][64 d][64 kk], swizzled
  ushort* PL = (ushort*)(arena + 32768);   // [128 q][64 kk] bf16, swizzled
  float* ob = (float*)arena;               // epilogue alias

  int tid = threadIdx.x;
  int qb = blockIdx.x, h = blockIdx.y, b = blockIdx.z;
  int n0 = qb * 128, bh = b * 8 + h;
  int lane = tid & 63, w = tid >> 6;
  int q15 = lane & 15, g = lane >> 4;

  const ushort* kbase = Kq + (size_t)bh * 256 * 64;
  const ushort* vbase = Vt + (size_t)bh * 64 * 256;

  bf16x8 qf[2][2];  // [set][kb], hi only
#pragma unroll
  for (int set = 0; set < 2; ++set) {
    const ushort* qptr =
        Qs + ((size_t)(b * 4096 + n0 + set * 64 + w * 16 + q15) * 8 + h) * 64;
#pragma unroll
    for (int kb = 0; kb < 2; ++kb)
      qf[set][kb] = *(const bf16x8*)(qptr + kb * 32 + g * 8);
  }

  f32x4 accO[2][4];
#pragma unroll
  for (int set = 0; set < 2; ++set)
#pragma unroll
    for (int t = 0; t < 4; ++t) accO[set][t] = (f32x4){0.f, 0.f, 0.f, 0.f};
  float m[2] = {-1e30f, -1e30f}, l[2] = {0.f, 0.f};

  // K rows [64 kk][64], V rows [64 d][64 kk]: 8 rows per 16B-lane instr.
#define STAGE_A(cc, buf)                                                     \
  {                                                                          \
    _Pragma("unroll") for (int i = 0; i < 2; ++i) {                          \
      int rb_ = w * 16 + i * 8;                                              \
      int r_ = rb_ + (lane >> 3);                                            \
      int sb_ = (lane & 7) ^ (r_ & 7);                                       \
      gload16(kbase + (size_t)((cc) * 64 + r_) * 64 + (sb_ << 3),            \
              KsL + (buf) * 4096 + rb_ * 64);                                \
      gload16(vbase + (size_t)r_ * 256 + (cc) * 64 + (sb_ << 3),             \
              VtL + (buf) * 4096 + rb_ * 64);                                \
    }                                                                        \
  }

  STAGE_A(0, 0);
  __syncthreads();

  for (int c = 0; c < 4; ++c) {
    int buf = c & 1;
    if (c < 3) STAGE_A(c + 1, buf ^ 1);
    const ushort* Ks = KsL + buf * 4096;
    const ushort* Vs = VtL + buf * 4096;

    // S^T = Khi * Qhi (1-term)
    f32x4 accS[2][4];
#pragma unroll
    for (int set = 0; set < 2; ++set)
#pragma unroll
      for (int t = 0; t < 4; ++t) accS[set][t] = (f32x4){0.f, 0.f, 0.f, 0.f};
#pragma unroll
    for (int kb = 0; kb < 2; ++kb) {
      bf16x8 ak[4];
#pragma unroll
      for (int t = 0; t < 4; ++t) {
        int kkr = t * 16 + q15;
        ak[t] = *(const bf16x8*)&Ks[kkr * 64 + (((kb * 4 + g) ^ (kkr & 7)) << 3)];
      }
#pragma unroll
      for (int set = 0; set < 2; ++set)
#pragma unroll
        for (int t = 0; t < 4; ++t)
          accS[set][t] = __builtin_amdgcn_mfma_f32_16x16x32_bf16(
              ak[t], qf[set][kb], accS[set][t], 0, 0, 0);
    }

#pragma unroll
    for (int set = 0; set < 2; ++set) {
      int qrowL = set * 64 + w * 16 + q15;
      float mx = -1e30f;
#pragma unroll
      for (int t = 0; t < 4; ++t)
#pragma unroll
        for (int r = 0; r < 4; ++r) mx = fmaxf(mx, accS[set][t][r]);
      mx = fmaxf(mx, __shfl_xor(mx, 16));
      mx = fmaxf(mx, __shfl_xor(mx, 32));
      float mn = fmaxf(m[set], mx);
      float fac = __expf(m[set] - mn);
      m[set] = mn;
      float sum = 0.f;
      ushort ph[4][4];
#pragma unroll
      for (int t = 0; t < 4; ++t)
#pragma unroll
        for (int r = 0; r < 4; ++r) {
          float p = __expf(accS[set][t][r] - mn);
          ushort hp = f2bf(p);
          ph[t][r] = hp;
          sum += bf2f(hp);
        }
      sum += __shfl_xor(sum, 16);
      sum += __shfl_xor(sum, 32);
      l[set] = l[set] * fac + sum;
#pragma unroll
      for (int t = 0; t < 4; ++t) {
        accO[set][t][0] *= fac; accO[set][t][1] *= fac;
        accO[set][t][2] *= fac; accO[set][t][3] *= fac;
      }
#pragma unroll
      for (int t = 0; t < 4; ++t)
#pragma unroll
        for (int rp = 0; rp < 4; rp += 2) {
          uint u = ph[t][rp] | ((uint)ph[t][rp + 1] << 16);
          int kkl = t * 16 + g * 4 + rp;
          int blk = kkl >> 3, off = kkl & 7;
          *(uint*)((char*)PL + qrowL * 128 + ((blk ^ (q15 & 7)) << 4) + off * 2) = u;
        }
    }
    __syncthreads();

    bf16x8 pf[2][2];
#pragma unroll
    for (int set = 0; set < 2; ++set) {
      int qrowL = set * 64 + w * 16 + q15;
#pragma unroll
      for (int kb = 0; kb < 2; ++kb)
        pf[set][kb] = *(const bf16x8*)((char*)PL + qrowL * 128 +
                                       (((kb * 4 + g) ^ (q15 & 7)) << 4));
    }
    // out^T += Vhi * P^T (1-term)
#pragma unroll
    for (int kb = 0; kb < 2; ++kb)
#pragma unroll
      for (int t = 0; t < 4; ++t) {
        int d = t * 16 + q15;
        bf16x8 vf =
            *(const bf16x8*)&Vs[d * 64 + (((kb * 4 + g) ^ (d & 7)) << 3)];
        accO[0][t] = __builtin_amdgcn_mfma_f32_16x16x32_bf16(vf, pf[0][kb],
                                                             accO[0][t], 0, 0, 0);
        accO[1][t] = __builtin_amdgcn_mfma_f32_16x16x32_bf16(vf, pf[1][kb],
                                                             accO[1][t], 0, 0, 0);
      }
    __syncthreads();
  }
#undef STAGE_A

#pragma unroll
  for (int set = 0; set < 2; ++set) {
    if (set) __syncthreads();
    float inv = 1.0f / l[set];
#pragma unroll
    for (int t = 0; t < 4; ++t)
#pragma unroll
      for (int r = 0; r < 4; ++r)
        ob[(t * 16 + g * 4 + r) * 68 + w * 16 + q15] = accO[set][t][r] * inv;
    __syncthreads();
#pragma unroll
    for (int i = 0; i < 2; ++i) {
      int idx = tid + i * 256;
      int qq = idx >> 3, d8 = (idx & 7) << 3;
      ushort hh[8];
#pragma unroll
      for (int jj = 0; jj < 8; ++jj) hh[jj] = f2bf(ob[(d8 + jj) * 68 + qq]);
      uint4 hp;
      hp.x = hh[0] | ((uint)hh[1] << 16); hp.y = hh[2] | ((uint)hh[3] << 16);
      hp.z = hh[4] | ((uint)hh[5] << 16); hp.w = hh[6] | ((uint)hh[7] << 16);
      size_t rowb = (size_t)(b * 4096 + n0 + set * 64 + qq) * 512 + h * 64 + d8;
      *(uint4*)(attno + rowb) = hp;
    }
  }
}

// ---------------- launch ----------------
extern "C" void kernel_launch(void* const* d_in, const int* in_sizes, int n_in,
                              void* d_out, int out_size, void* d_ws, size_t ws_size,
                              hipStream_t stream) {
  const float* x     = (const float*)d_in[0];
  const float* Wq    = (const float*)d_in[1];
  const float* bq    = (const float*)d_in[2];
  const float* Wk    = (const float*)d_in[3];
  const float* bk    = (const float*)d_in[4];
  const float* Wv    = (const float*)d_in[5];
  const float* bv    = (const float*)d_in[6];
  const float* Wp    = (const float*)d_in[7];
  const float* bp    = (const float*)d_in[8];
  const float* Wsr   = (const float*)d_in[9];
  const float* bsr   = (const float*)d_in[10];
  const float* gamma = (const float*)d_in[11];
  const float* beta  = (const float*)d_in[12];

  float* ws = (float*)d_ws;
  // Layout (~64MB):
  //   xq hi [16384][512] us = 4,194,304 fl (attno_ aliases after qkv)
  //   conv_part [16][1024][512] f32 = 8,388,608 fl at +4,194,304
  //     (Qsplit 8,388,608 us = 4,194,304 fl aliases, written after ln)
  //   Wsr_ 4,194,304 us = 2,097,152 fl at +12,582,912
  //   rest at +14,680,064
  ushort* xq     = (ushort*)ws;
  ushort* attno_ = (ushort*)ws;
  float*  conv_part = ws + 4194304;
  ushort* Qsplit = (ushort*)(ws + 4194304);
  ushort* Wsr_ = (ushort*)(ws + 12582912);
  float*  rest = ws + 14680064;
  ushort* Wq_  = (ushort*)rest;                 // 262,144 us = 131,072 fl
  ushort* Wp_  = (ushort*)(rest + 131072);      // 262,144 us
  ushort* Wkv_ = (ushort*)(rest + 262144);      // 524,288 us = 262,144 fl
  ushort* xkv_ = (ushort*)(rest + 524288);      // 524,288 us
  ushort* Kq   = (ushort*)(rest + 786432);      // 524,288 us
  ushort* Vt   = (ushort*)(rest + 1048576);     // 524,288 us
  float*  bkv  = rest + 1310720;                // 1,024 fl
  float* outp = (float*)d_out;

  prep_kernel<<<8705, 256, 0, stream>>>(x, Wq, Wp, Wk, Wv, Wsr, bk, bv,
                                        xq, Wq_, Wp_, Wkv_, Wsr_, bkv);
  conv_kernel<<<512, 256, 0, stream>>>(xq, Wsr_, conv_part);
  ln_kernel<<<1024, 256, 0, stream>>>(conv_part, bsr, gamma, beta, xkv_);
  qkv_kernel<<<576, 256, 0, stream>>>(xq, Wq_, bq, Qsplit,
                                      xkv_, Wkv_, bkv, Kq, Vt);
  attn_kernel<<<dim3(32, 8, 4), 256, 0, stream>>>(Qsplit, Kq, Vt, attno_);
  gemm_out_kernel<<<512, 256, 0, stream>>>(attno_, Wp_, bp, outp);
}

// Round 18
// 97.723 us; speedup vs baseline: 1.7816x; 1.0195x over previous
//
#include <hip/hip_runtime.h>

// B=4, H=W=64, N=4096, C=512, HEAD=8, dh=64, SR=4, Nk=256
// Full bf16 pipeline (validated: absmax 4.88e-4 vs 1.26e-3 threshold):
//   all GEMMs pure bf16 (K=512, 8 K-steps), fp32 MFMA accumulate;
//   attn QK 1-term, PV 1-term; Q/K/V/attno hi-only; conv partials bf16.

typedef __bf16 bf16x8 __attribute__((ext_vector_type(8)));
typedef float f32x4 __attribute__((ext_vector_type(4)));

__device__ __forceinline__ ushort f2bf(float v) {
  uint u = __float_as_uint(v);
  return (ushort)((u + 0x7FFFu + ((u >> 16) & 1u)) >> 16);
}
__device__ __forceinline__ float bf2f(ushort h) {
  return __uint_as_float((uint)h << 16);
}
__device__ __forceinline__ void gload16(const void* g, void* l) {
  __builtin_amdgcn_global_load_lds(
      (const __attribute__((address_space(1))) void*)g,
      (__attribute__((address_space(3))) void*)l, 16, 0, 0);
}
// bijective XCD swizzle for nwg % 8 == 0
__device__ __forceinline__ int xcd_swz(int bid, int nwg) {
  int cpx = nwg >> 3;
  return (bid & 7) * cpx + (bid >> 3);
}

// ---------------- fused prep: everything -> hi-only bf16 ----------------
__global__ __launch_bounds__(256) void prep_kernel(
    const float* __restrict__ x, const float* __restrict__ Wq,
    const float* __restrict__ Wp, const float* __restrict__ Wk,
    const float* __restrict__ Wv, const float* __restrict__ Wsr,
    const float* __restrict__ bk, const float* __restrict__ bv,
    ushort* __restrict__ xq, ushort* __restrict__ Wq_,
    ushort* __restrict__ Wp_, ushort* __restrict__ Wkv_,
    ushort* __restrict__ Wsr_, float* __restrict__ bkv) {
  __shared__ float t[32][33];
  int bid = blockIdx.x, tid = threadIdx.x;
  if (bid < 4096 + 512) {
    const float* src;
    ushort* dst;
    int gid;
    if (bid < 4096) {
      src = x; dst = xq; gid = bid * 256 + tid;
    } else {
      int z = (bid - 4096) >> 7;
      src = (z == 0) ? Wq : (z == 1) ? Wp : (z == 2) ? Wk : Wv;
      dst = (z == 0) ? Wq_ : (z == 1) ? Wp_ : (z == 2) ? Wkv_ : (Wkv_ + 512 * 512);
      gid = ((bid - 4096) & 127) * 256 + tid;
    }
    int row = gid >> 6, c8 = (gid & 63) << 3;
    float4 a = *(const float4*)(src + (size_t)row * 512 + c8);
    float4 b = *(const float4*)(src + (size_t)row * 512 + c8 + 4);
    ushort h[8];
    float vv[8] = {a.x, a.y, a.z, a.w, b.x, b.y, b.z, b.w};
#pragma unroll
    for (int e = 0; e < 8; ++e) h[e] = f2bf(vv[e]);
    uint4 hp;
    hp.x = h[0] | ((uint)h[1] << 16); hp.y = h[2] | ((uint)h[3] << 16);
    hp.z = h[4] | ((uint)h[5] << 16); hp.w = h[6] | ((uint)h[7] << 16);
    *(uint4*)(dst + (size_t)row * 512 + c8) = hp;
  } else if (bid < 4096 + 512 + 4096) {
    int tb = bid - 4608;
    int z = tb >> 8, rem = tb & 255;
    int ci0 = (rem >> 4) << 5, co0 = (rem & 15) << 5;
    int tx = tid & 31, ty = tid >> 5;
#pragma unroll
    for (int i = 0; i < 32; i += 8)
      t[ty + i][tx] = Wsr[((size_t)z * 512 + ci0 + ty + i) * 512 + co0 + tx];
    __syncthreads();
#pragma unroll
    for (int i = 0; i < 32; i += 8) {
      float v = t[tx][ty + i];
      int co = co0 + ty + i, ci = ci0 + tx;
      Wsr_[((size_t)z * 512 + co) * 512 + ci] = f2bf(v);
    }
  } else {
    bkv[tid] = bk[tid]; bkv[tid + 256] = bk[tid + 256];
    bkv[tid + 512] = bv[tid]; bkv[tid + 768] = bv[tid + 256];
  }
}

// ---------------- MFMA GEMM body: pure bf16, 8 K-steps, dbuf 2-phase ----------------
// EPI=0: C fp32 + bias. EPI=1: Q hi-only per-head layout. EPI=2: Kq/Vt scatter.
template <int EPI>
__device__ __forceinline__ void gemm_body(
    const ushort* __restrict__ A, const ushort* __restrict__ Bw,
    const float* __restrict__ bias, float* __restrict__ C,
    ushort* __restrict__ Qs, ushort* __restrict__ Kq, ushort* __restrict__ Vt,
    int N, int bx, int by, ushort* lds) {
  int tid = threadIdx.x;
  int lane = tid & 63, w = tid >> 6;
  int wr = w >> 1, wc = w & 1;
  int l15 = lane & 15, g = lane >> 4;
  int srow = lane >> 3;
  int scol = (lane & 7) ^ srow;

  const ushort* aBase = A + (size_t)(by * 128 + w * 32 + srow) * 512 + scol * 8;
  const ushort* bBase = Bw + (size_t)(bx * 128 + w * 32 + srow) * 512 + scol * 8;

  f32x4 acc[4][4];
#pragma unroll
  for (int i = 0; i < 4; ++i)
#pragma unroll
    for (int j = 0; j < 4; ++j) acc[i][j] = (f32x4){0.f, 0.f, 0.f, 0.f};

#define STAGE_G(ks, buf)                                              \
  {                                                                   \
    int kk = (ks) * 64;                                               \
    ushort* aD = lds + (buf) * 16384 + w * 2048;                      \
    ushort* bD = lds + (buf) * 16384 + 8192 + w * 2048;               \
    _Pragma("unroll") for (int t = 0; t < 4; ++t) {                   \
      gload16(aBase + (size_t)t * 4096 + kk, aD + t * 512);           \
      gload16(bBase + (size_t)t * 4096 + kk, bD + t * 512);           \
    }                                                                 \
  }

#define COMPUTE_G(buf)                                                         \
  {                                                                            \
    const ushort* As = lds + (buf) * 16384;                                    \
    const ushort* Bs = As + 8192;                                              \
    _Pragma("unroll") for (int kk2 = 0; kk2 < 2; ++kk2) {                      \
      int rb = kk2 * 4 + g;                                                    \
      bf16x8 af[4], bg[4];                                                     \
      _Pragma("unroll") for (int i = 0; i < 4; ++i) {                          \
        int row = wr * 64 + i * 16 + l15;                                      \
        af[i] = *(const bf16x8*)&As[row * 64 + ((rb ^ (row & 7)) << 3)];       \
      }                                                                        \
      _Pragma("unroll") for (int j = 0; j < 4; ++j) {                          \
        int col = wc * 64 + j * 16 + l15;                                      \
        bg[j] = *(const bf16x8*)&Bs[col * 64 + ((rb ^ (col & 7)) << 3)];       \
      }                                                                        \
      _Pragma("unroll") for (int i = 0; i < 4; ++i)                            \
        _Pragma("unroll") for (int j = 0; j < 4; ++j)                          \
          acc[i][j] =                                                          \
              __builtin_amdgcn_mfma_f32_16x16x32_bf16(af[i], bg[j], acc[i][j], \
                                                      0, 0, 0);                \
    }                                                                          \
  }

  STAGE_G(0, 0);
  __syncthreads();
  for (int ks = 0; ks < 7; ++ks) {
    STAGE_G(ks + 1, (ks + 1) & 1);
    COMPUTE_G(ks & 1);
    __syncthreads();
  }
  COMPUTE_G(1);

#undef STAGE_G
#undef COMPUTE_G

  if (EPI == 0) {
#pragma unroll
    for (int j = 0; j < 4; ++j) {
      int col = bx * 128 + wc * 64 + j * 16 + l15;
      float bj = bias ? bias[col] : 0.f;
#pragma unroll
      for (int i = 0; i < 4; ++i) {
        int row0 = by * 128 + wr * 64 + i * 16 + g * 4;
#pragma unroll
        for (int r = 0; r < 4; ++r)
          C[(size_t)(row0 + r) * N + col] = acc[i][j][r] + bj;
      }
    }
  } else if (EPI == 1) {
    __syncthreads();
#pragma unroll
    for (int j = 0; j < 4; ++j) {
      int cl = wc * 64 + j * 16 + l15;
      float bj = bias[bx * 128 + cl];
#pragma unroll
      for (int i = 0; i < 4; ++i) {
        int rl0 = wr * 64 + i * 16 + g * 4;
#pragma unroll
        for (int r = 0; r < 4; ++r)
          lds[(rl0 + r) * 128 + cl] = f2bf((acc[i][j][r] + bj) * 0.125f);
      }
    }
    __syncthreads();
#pragma unroll
    for (int it = 0; it < 8; ++it) {
      int c = tid + it * 256;
      int r = c >> 4, ck = c & 15;
      int grow = by * 128 + r;
      size_t base = ((size_t)grow * 8 + bx * 2 + (ck >> 3)) * 64 + (ck & 7) * 8;
      *(uint4*)(Qs + base) = *(const uint4*)&lds[r * 128 + ck * 8];
    }
  } else {
#pragma unroll
    for (int j = 0; j < 4; ++j) {
      int col = bx * 128 + wc * 64 + j * 16 + l15;
      float bj = bias[col];
      bool isK = col < 512;
      int cp = isK ? col : col - 512;
      int hh = cp >> 6, d = cp & 63;
#pragma unroll
      for (int i = 0; i < 4; ++i) {
        int row0 = by * 128 + wr * 64 + i * 16 + g * 4;
#pragma unroll
        for (int r = 0; r < 4; ++r) {
          int row = row0 + r;
          int b = row >> 8, kk = row & 255;
          ushort h = f2bf(acc[i][j][r] + bj);
          if (isK)
            Kq[((size_t)((b * 8 + hh) * 256) + kk) * 64 + d] = h;
          else
            Vt[((size_t)((b * 8 + hh) * 64) + d) * 256 + kk] = h;
        }
      }
    }
  }
}

// ---------------- conv body: one tap per block, bf16 partials out ----------------
__device__ __forceinline__ void conv_body(
    const ushort* __restrict__ xq, const ushort* __restrict__ Wsr_,
    ushort* __restrict__ part, int bx, int by, int z, ushort* lds) {
  int kh = z >> 2, kw = z & 3;
  int tid = threadIdx.x;
  int lane = tid & 63, w = tid >> 6;
  int wr = w >> 1, wc = w & 1;
  int l15 = lane & 15, g = lane >> 4;
  int srow = lane >> 3;
  int scol = (lane & 7) ^ srow;

  const ushort* aBase[4];
#pragma unroll
  for (int t = 0; t < 4; ++t) {
    int gm = by * 128 + w * 32 + t * 8 + srow;
    int xr = (gm >> 8) * 4096 + ((((gm >> 4) & 15) << 2) + kh) * 64 +
             ((gm & 15) << 2) + kw;
    aBase[t] = xq + (size_t)xr * 512 + scol * 8;
  }
  const ushort* bBase =
      Wsr_ + ((size_t)(z * 512 + bx * 128 + w * 32 + srow)) * 512 + scol * 8;

  f32x4 acc[4][4];
#pragma unroll
  for (int i = 0; i < 4; ++i)
#pragma unroll
    for (int j = 0; j < 4; ++j) acc[i][j] = (f32x4){0.f, 0.f, 0.f, 0.f};

#define STAGE_C(ks, buf)                                              \
  {                                                                   \
    int kk = (ks) * 64;                                               \
    ushort* aD = lds + (buf) * 16384 + w * 2048;                      \
    ushort* bD = lds + (buf) * 16384 + 8192 + w * 2048;               \
    _Pragma("unroll") for (int t = 0; t < 4; ++t) {                   \
      gload16(aBase[t] + kk, aD + t * 512);                           \
      gload16(bBase + (size_t)t * 4096 + kk, bD + t * 512);           \
    }                                                                 \
  }

#define COMPUTE_C(buf)                                                         \
  {                                                                            \
    const ushort* As = lds + (buf) * 16384;                                    \
    const ushort* Bs = As + 8192;                                              \
    _Pragma("unroll") for (int kk2 = 0; kk2 < 2; ++kk2) {                      \
      int rb = kk2 * 4 + g;                                                    \
      bf16x8 af[4], bg[4];                                                     \
      _Pragma("unroll") for (int i = 0; i < 4; ++i) {                          \
        int row = wr * 64 + i * 16 + l15;                                      \
        af[i] = *(const bf16x8*)&As[row * 64 + ((rb ^ (row & 7)) << 3)];       \
      }                                                                        \
      _Pragma("unroll") for (int j = 0; j < 4; ++j) {                          \
        int col = wc * 64 + j * 16 + l15;                                      \
        bg[j] = *(const bf16x8*)&Bs[col * 64 + ((rb ^ (col & 7)) << 3)];       \
      }                                                                        \
      _Pragma("unroll") for (int i = 0; i < 4; ++i)                            \
        _Pragma("unroll") for (int j = 0; j < 4; ++j)                          \
          acc[i][j] =                                                          \
              __builtin_amdgcn_mfma_f32_16x16x32_bf16(af[i], bg[j], acc[i][j], \
                                                      0, 0, 0);                \
    }                                                                          \
  }

  STAGE_C(0, 0);
  __syncthreads();
  for (int ks = 0; ks < 7; ++ks) {
    STAGE_C(ks + 1, (ks + 1) & 1);
    COMPUTE_C(ks & 1);
    __syncthreads();
  }
  COMPUTE_C(1);

#undef STAGE_C
#undef COMPUTE_C

  ushort* Cp = part + (size_t)z * 524288;
#pragma unroll
  for (int j = 0; j < 4; ++j) {
    int col = bx * 128 + wc * 64 + j * 16 + l15;
#pragma unroll
    for (int i = 0; i < 4; ++i) {
      int row0 = by * 128 + wr * 64 + i * 16 + g * 4;
#pragma unroll
      for (int r = 0; r < 4; ++r)
        Cp[(size_t)(row0 + r) * 512 + col] = f2bf(acc[i][j][r]);
    }
  }
}

// conv: 512 blocks, uniform 8 steps
__global__ __launch_bounds__(256) void conv_kernel(
    const ushort* __restrict__ xq, const ushort* __restrict__ Wsr_,
    ushort* __restrict__ part) {
  __shared__ __align__(16) ushort lds[32768];
  int bid = xcd_swz(blockIdx.x, 512);
  conv_body(xq, Wsr_, part, bid & 3, (bid >> 2) & 7, bid >> 5, lds);
}

// q-proj (512) + kv-proj (64): 576 uniform 8-step blocks.
__global__ __launch_bounds__(256) void qkv_kernel(
    const ushort* __restrict__ xq, const ushort* __restrict__ Wq_,
    const float* __restrict__ bq, ushort* __restrict__ Qs,
    const ushort* __restrict__ xkv_, const ushort* __restrict__ Wkv_,
    const float* __restrict__ bkv, ushort* __restrict__ Kq,
    ushort* __restrict__ Vt) {
  __shared__ __align__(16) ushort lds[32768];
  int n = blockIdx.x;  // 576
  int xcd = n & 7, slot = n >> 3;
  if (slot < 8) {
    int id = xcd * 8 + slot;  // 0..63
    gemm_body<2>(xkv_, Wkv_, bkv, nullptr, nullptr, Kq, Vt, 1024,
                 id & 7, id >> 3, lds);
  } else {
    int id = xcd * 64 + (slot - 8);  // 0..511
    gemm_body<1>(xq, Wq_, bq, nullptr, Qs, nullptr, nullptr, 512,
                 id & 3, id >> 2, lds);
  }
}

// out-proj
__global__ __launch_bounds__(256) void gemm_out_kernel(
    const ushort* __restrict__ A, const ushort* __restrict__ Bw,
    const float* __restrict__ bias, float* __restrict__ C) {
  __shared__ __align__(16) ushort lds[32768];
  int bid = xcd_swz(blockIdx.x, 512);
  gemm_body<0>(A, Bw, bias, C, nullptr, nullptr, nullptr, 512,
               bid & 3, bid >> 2, lds);
}

// ---------------- partial-sum(16, bf16) + bias + LayerNorm -> bf16 ----------------
__global__ __launch_bounds__(256) void ln_kernel(
    const ushort* __restrict__ part, const float* __restrict__ bsr,
    const float* __restrict__ gamma, const float* __restrict__ beta,
    ushort* __restrict__ xkv_) {
  int row = blockIdx.x;
  int t = threadIdx.x;
  float v0 = bsr[t], v1 = bsr[t + 256];
  for (int p = 0; p < 16; ++p) {
    v0 += bf2f(part[(size_t)p * 524288 + (size_t)row * 512 + t]);
    v1 += bf2f(part[(size_t)p * 524288 + (size_t)row * 512 + t + 256]);
  }
  float s = v0 + v1, sq = v0 * v0 + v1 * v1;
#pragma unroll
  for (int o = 1; o < 64; o <<= 1) {
    s += __shfl_xor(s, o);
    sq += __shfl_xor(sq, o);
  }
  __shared__ float red[8];
  int wv = t >> 6;
  if ((t & 63) == 0) { red[wv] = s; red[4 + wv] = sq; }
  __syncthreads();
  s = red[0] + red[1] + red[2] + red[3];
  sq = red[4] + red[5] + red[6] + red[7];
  float mu = s * (1.0f / 512.0f);
  float var = sq * (1.0f / 512.0f) - mu * mu;
  float rs = rsqrtf(var + 1e-5f);
  xkv_[(size_t)row * 512 + t] = f2bf((v0 - mu) * rs * gamma[t] + beta[t]);
  xkv_[(size_t)row * 512 + t + 256] =
      f2bf((v1 - mu) * rs * gamma[t + 256] + beta[t + 256]);
}

// ---------------- MFMA flash attention: 128 q/block, 1-term QK & PV ----------------
__global__ __launch_bounds__(256, 3) void attn_kernel(
    const ushort* __restrict__ Qs, const ushort* __restrict__ Kq,
    const ushort* __restrict__ Vt, ushort* __restrict__ attno) {
  __shared__ __align__(16) char arena[49152];
  ushort* KsL = (ushort*)arena;            // [2][64 kk][64], swizzled
  ushort* VtL = (ushort*)(arena + 16384);  // [2][64 d][64 kk], swizzled
  ushort* PL = (ushort*)(arena + 32768);   // [128 q][64 kk] bf16, swizzled
  float* ob = (float*)arena;               // epilogue alias

  int tid = threadIdx.x;
  int qb = blockIdx.x, h = blockIdx.y, b = blockIdx.z;
  int n0 = qb * 128, bh = b * 8 + h;
  int lane = tid & 63, w = tid >> 6;
  int q15 = lane & 15, g = lane >> 4;

  const ushort* kbase = Kq + (size_t)bh * 256 * 64;
  const ushort* vbase = Vt + (size_t)bh * 64 * 256;

  bf16x8 qf[2][2];
#pragma unroll
  for (int set = 0; set < 2; ++set) {
    const ushort* qptr =
        Qs + ((size_t)(b * 4096 + n0 + set * 64 + w * 16 + q15) * 8 + h) * 64;
#pragma unroll
    for (int kb = 0; kb < 2; ++kb)
      qf[set][kb] = *(const bf16x8*)(qptr + kb * 32 + g * 8);
  }

  f32x4 accO[2][4];
#pragma unroll
  for (int set = 0; set < 2; ++set)
#pragma unroll
    for (int t = 0; t < 4; ++t) accO[set][t] = (f32x4){0.f, 0.f, 0.f, 0.f};
  float m[2] = {-1e30f, -1e30f}, l[2] = {0.f, 0.f};

#define STAGE_A(cc, buf)                                                     \
  {                                                                          \
    _Pragma("unroll") for (int i = 0; i < 2; ++i) {                          \
      int rb_ = w * 16 + i * 8;                                              \
      int r_ = rb_ + (lane >> 3);                                            \
      int sb_ = (lane & 7) ^ (r_ & 7);                                       \
      gload16(kbase + (size_t)((cc) * 64 + r_) * 64 + (sb_ << 3),            \
              KsL + (buf) * 4096 + rb_ * 64);                                \
      gload16(vbase + (size_t)r_ * 256 + (cc) * 64 + (sb_ << 3),             \
              VtL + (buf) * 4096 + rb_ * 64);                                \
    }                                                                        \
  }

  STAGE_A(0, 0);
  __syncthreads();

  for (int c = 0; c < 4; ++c) {
    int buf = c & 1;
    if (c < 3) STAGE_A(c + 1, buf ^ 1);
    const ushort* Ks = KsL + buf * 4096;
    const ushort* Vs = VtL + buf * 4096;

    f32x4 accS[2][4];
#pragma unroll
    for (int set = 0; set < 2; ++set)
#pragma unroll
      for (int t = 0; t < 4; ++t) accS[set][t] = (f32x4){0.f, 0.f, 0.f, 0.f};
#pragma unroll
    for (int kb = 0; kb < 2; ++kb) {
      bf16x8 ak[4];
#pragma unroll
      for (int t = 0; t < 4; ++t) {
        int kkr = t * 16 + q15;
        ak[t] = *(const bf16x8*)&Ks[kkr * 64 + (((kb * 4 + g) ^ (kkr & 7)) << 3)];
      }
#pragma unroll
      for (int set = 0; set < 2; ++set)
#pragma unroll
        for (int t = 0; t < 4; ++t)
          accS[set][t] = __builtin_amdgcn_mfma_f32_16x16x32_bf16(
              ak[t], qf[set][kb], accS[set][t], 0, 0, 0);
    }

#pragma unroll
    for (int set = 0; set < 2; ++set) {
      int qrowL = set * 64 + w * 16 + q15;
      float mx = -1e30f;
#pragma unroll
      for (int t = 0; t < 4; ++t)
#pragma unroll
        for (int r = 0; r < 4; ++r) mx = fmaxf(mx, accS[set][t][r]);
      mx = fmaxf(mx, __shfl_xor(mx, 16));
      mx = fmaxf(mx, __shfl_xor(mx, 32));
      float mn = fmaxf(m[set], mx);
      float fac = __expf(m[set] - mn);
      m[set] = mn;
      float sum = 0.f;
      ushort ph[4][4];
#pragma unroll
      for (int t = 0; t < 4; ++t)
#pragma unroll
        for (int r = 0; r < 4; ++r) {
          float p = __expf(accS[set][t][r] - mn);
          ushort hp = f2bf(p);
          ph[t][r] = hp;
          sum += bf2f(hp);
        }
      sum += __shfl_xor(sum, 16);
      sum += __shfl_xor(sum, 32);
      l[set] = l[set] * fac + sum;
#pragma unroll
      for (int t = 0; t < 4; ++t) {
        accO[set][t][0] *= fac; accO[set][t][1] *= fac;
        accO[set][t][2] *= fac; accO[set][t][3] *= fac;
      }
#pragma unroll
      for (int t = 0; t < 4; ++t)
#pragma unroll
        for (int rp = 0; rp < 4; rp += 2) {
          uint u = ph[t][rp] | ((uint)ph[t][rp + 1] << 16);
          int kkl = t * 16 + g * 4 + rp;
          int blk = kkl >> 3, off = kkl & 7;
          *(uint*)((char*)PL + qrowL * 128 + ((blk ^ (q15 & 7)) << 4) + off * 2) = u;
        }
    }
    __syncthreads();

    bf16x8 pf[2][2];
#pragma unroll
    for (int set = 0; set < 2; ++set) {
      int qrowL = set * 64 + w * 16 + q15;
#pragma unroll
      for (int kb = 0; kb < 2; ++kb)
        pf[set][kb] = *(const bf16x8*)((char*)PL + qrowL * 128 +
                                       (((kb * 4 + g) ^ (q15 & 7)) << 4));
    }
#pragma unroll
    for (int kb = 0; kb < 2; ++kb)
#pragma unroll
      for (int t = 0; t < 4; ++t) {
        int d = t * 16 + q15;
        bf16x8 vf =
            *(const bf16x8*)&Vs[d * 64 + (((kb * 4 + g) ^ (d & 7)) << 3)];
        accO[0][t] = __builtin_amdgcn_mfma_f32_16x16x32_bf16(vf, pf[0][kb],
                                                             accO[0][t], 0, 0, 0);
        accO[1][t] = __builtin_amdgcn_mfma_f32_16x16x32_bf16(vf, pf[1][kb],
                                                             accO[1][t], 0, 0, 0);
      }
    __syncthreads();
  }
#undef STAGE_A

#pragma unroll
  for (int set = 0; set < 2; ++set) {
    if (set) __syncthreads();
    float inv = 1.0f / l[set];
#pragma unroll
    for (int t = 0; t < 4; ++t)
#pragma unroll
      for (int r = 0; r < 4; ++r)
        ob[(t * 16 + g * 4 + r) * 68 + w * 16 + q15] = accO[set][t][r] * inv;
    __syncthreads();
#pragma unroll
    for (int i = 0; i < 2; ++i) {
      int idx = tid + i * 256;
      int qq = idx >> 3, d8 = (idx & 7) << 3;
      ushort hh[8];
#pragma unroll
      for (int jj = 0; jj < 8; ++jj) hh[jj] = f2bf(ob[(d8 + jj) * 68 + qq]);
      uint4 hp;
      hp.x = hh[0] | ((uint)hh[1] << 16); hp.y = hh[2] | ((uint)hh[3] << 16);
      hp.z = hh[4] | ((uint)hh[5] << 16); hp.w = hh[6] | ((uint)hh[7] << 16);
      size_t rowb = (size_t)(b * 4096 + n0 + set * 64 + qq) * 512 + h * 64 + d8;
      *(uint4*)(attno + rowb) = hp;
    }
  }
}

// ---------------- launch ----------------
extern "C" void kernel_launch(void* const* d_in, const int* in_sizes, int n_in,
                              void* d_out, int out_size, void* d_ws, size_t ws_size,
                              hipStream_t stream) {
  const float* x     = (const float*)d_in[0];
  const float* Wq    = (const float*)d_in[1];
  const float* bq    = (const float*)d_in[2];
  const float* Wk    = (const float*)d_in[3];
  const float* bk    = (const float*)d_in[4];
  const float* Wv    = (const float*)d_in[5];
  const float* bv    = (const float*)d_in[6];
  const float* Wp    = (const float*)d_in[7];
  const float* bp    = (const float*)d_in[8];
  const float* Wsr   = (const float*)d_in[9];
  const float* bsr   = (const float*)d_in[10];
  const float* gamma = (const float*)d_in[11];
  const float* beta  = (const float*)d_in[12];

  float* ws = (float*)d_ws;
  // Layout (~47MB):
  //   xq [16384][512] us = 4,194,304 fl (attno_ aliases after qkv)
  //   conv_part [16][1024][512] us = 4,194,304 fl at +4,194,304
  //     (Qsplit 8,388,608 us aliases, written after ln)
  //   Wsr_ 4,194,304 us = 2,097,152 fl at +8,388,608
  //   rest at +10,485,760
  ushort* xq     = (ushort*)ws;
  ushort* attno_ = (ushort*)ws;
  ushort* conv_part = (ushort*)(ws + 4194304);
  ushort* Qsplit = (ushort*)(ws + 4194304);
  ushort* Wsr_ = (ushort*)(ws + 8388608);
  float*  rest = ws + 10485760;
  ushort* Wq_  = (ushort*)rest;                 // 262,144 us = 131,072 fl
  ushort* Wp_  = (ushort*)(rest + 131072);      // 262,144 us
  ushort* Wkv_ = (ushort*)(rest + 262144);      // 524,288 us = 262,144 fl
  ushort* xkv_ = (ushort*)(rest + 524288);      // 524,288 us
  ushort* Kq   = (ushort*)(rest + 786432);      // 524,288 us
  ushort* Vt   = (ushort*)(rest + 1048576);     // 524,288 us
  float*  bkv  = rest + 1310720;                // 1,024 fl
  float* outp = (float*)d_out;

  prep_kernel<<<8705, 256, 0, stream>>>(x, Wq, Wp, Wk, Wv, Wsr, bk, bv,
                                        xq, Wq_, Wp_, Wkv_, Wsr_, bkv);
  conv_kernel<<<512, 256, 0, stream>>>(xq, Wsr_, conv_part);
  ln_kernel<<<1024, 256, 0, stream>>>(conv_part, bsr, gamma, beta, xkv_);
  qkv_kernel<<<576, 256, 0, stream>>>(xq, Wq_, bq, Qsplit,
                                      xkv_, Wkv_, bkv, Kq, Vt);
  attn_kernel<<<dim3(32, 8, 4), 256, 0, stream>>>(Qsplit, Kq, Vt, attno_);
  gemm_out_kernel<<<512, 256, 0, stream>>>(attno_, Wp_, bp, outp);
}